// Round 1
// baseline (1057.506 us; speedup 1.0000x reference)
//
#include <hip/hip_runtime.h>
#include <math.h>

#define N_NODES 1500
#define N_EDGES 12000
#define IN_FEAT 512
#define HIDDEN 64
#define OUT_FEAT 32
#define HEADS 8

// ---------------- graph preprocessing (deterministic CSR by dst) ----------------

__global__ void zero_counts_kernel(int* counts) {
    int i = blockIdx.x * blockDim.x + threadIdx.x;
    if (i < N_NODES + 1) counts[i] = 0;
}

__global__ void hist_kernel(const int* __restrict__ dst, int* __restrict__ counts) {
    int e = blockIdx.x * blockDim.x + threadIdx.x;
    if (e < N_EDGES) atomicAdd(&counts[dst[e]], 1);
}

// rank[e] = #{e' < e : dst[e'] == dst[e]}  (deterministic stable order)
__global__ void rank_kernel(const int* __restrict__ dst, int* __restrict__ rnk) {
    int e = blockIdx.x * blockDim.x + threadIdx.x;
    if (e >= N_EDGES) return;
    int d = dst[e];
    int r = 0;
    for (int i = 0; i < e; ++i) r += (dst[i] == d) ? 1 : 0;
    rnk[e] = r;
}

__global__ void scan_kernel(const int* __restrict__ counts, int* __restrict__ row_ptr) {
    __shared__ int part[256];
    int t = threadIdx.x;
    const int CH = (N_NODES + 255) / 256; // 6
    int base = t * CH;
    int loc[8];
    int s = 0;
    for (int i = 0; i < CH; ++i) {
        int idx = base + i;
        int v = (idx < N_NODES) ? counts[idx] : 0;
        loc[i] = s;
        s += v;
    }
    part[t] = s;
    __syncthreads();
    if (t == 0) {
        int a = 0;
        for (int i = 0; i < 256; ++i) { int v = part[i]; part[i] = a; a += v; }
        row_ptr[N_NODES] = a;
    }
    __syncthreads();
    int p0 = part[t];
    for (int i = 0; i < CH; ++i) {
        int idx = base + i;
        if (idx < N_NODES) row_ptr[idx] = p0 + loc[i];
    }
}

__global__ void scatter_kernel(const int* __restrict__ dst, const int* __restrict__ rnk,
                               const int* __restrict__ row_ptr, int* __restrict__ edge_idx) {
    int e = blockIdx.x * blockDim.x + threadIdx.x;
    if (e < N_EDGES) edge_idx[row_ptr[dst[e]] + rnk[e]] = e;
}

// ---------------- f32 tiled GEMM (layer 1 only): C[M,N] = A[M,K] @ B[K,N] ----------------
// K % 16 == 0, N % 64 == 0 required; M guarded.

#define BM 64
#define BN 64
#define BK 16

__global__ __launch_bounds__(256) void gemm_f32(const float* __restrict__ A,
                                                const float* __restrict__ B,
                                                float* __restrict__ C,
                                                int M, int N, int K) {
    __shared__ float As[BK][BM + 4]; // [k][m], pad to 68 floats
    __shared__ float Bs[BK][BN + 4];
    int t = threadIdx.x;
    int col0 = blockIdx.x * BN, row0 = blockIdx.y * BM;
    int tx = t & 15, ty = t >> 4;
    float acc[4][4] = {};
    for (int k0 = 0; k0 < K; k0 += BK) {
        {
            int k = t & 15, m0 = t >> 4;
            #pragma unroll
            for (int i = 0; i < 4; ++i) {
                int m = m0 + 16 * i;
                int gr = row0 + m;
                As[k][m] = (gr < M) ? A[(size_t)gr * K + k0 + k] : 0.0f;
            }
        }
        {
            int n = t & 63, k4 = t >> 6;
            #pragma unroll
            for (int i = 0; i < 4; ++i) {
                int k = k4 * 4 + i;
                Bs[k][n] = B[(size_t)(k0 + k) * N + col0 + n];
            }
        }
        __syncthreads();
        #pragma unroll
        for (int kk = 0; kk < BK; ++kk) {
            float4 a4 = *(const float4*)&As[kk][ty * 4];
            float4 b4 = *(const float4*)&Bs[kk][tx * 4];
            float av[4] = {a4.x, a4.y, a4.z, a4.w};
            float bv[4] = {b4.x, b4.y, b4.z, b4.w};
            #pragma unroll
            for (int i = 0; i < 4; ++i)
                #pragma unroll
                for (int j = 0; j < 4; ++j)
                    acc[i][j] = fmaf(av[i], bv[j], acc[i][j]);
        }
        __syncthreads();
    }
    #pragma unroll
    for (int i = 0; i < 4; ++i) {
        int gr = row0 + ty * 4 + i;
        if (gr < M) {
            float4 v = make_float4(acc[i][0], acc[i][1], acc[i][2], acc[i][3]);
            *(float4*)&C[(size_t)gr * N + col0 + tx * 4] = v;
        }
    }
}

// ---------------- attention-vector transforms ----------------

// out[h,k] = sum_f W[k, h*Fo+f] * a[h,f]   (W: [K, HEADS*Fo], out: [HEADS,K])
__global__ void att_eff_kernel(const float* __restrict__ W, const float* __restrict__ a,
                               float* __restrict__ out, int K, int Fo) {
    int idx = blockIdx.x * blockDim.x + threadIdx.x;
    if (idx >= HEADS * K) return;
    int h = idx / K, k = idx - h * K;
    float s = 0.f;
    for (int f = 0; f < Fo; ++f)
        s = fmaf(W[(size_t)k * (HEADS * Fo) + h * Fo + f], a[h * Fo + f], s);
    out[idx] = s;
}

// layer-1: el/er per (n,h) row of feat1 [N*8, 64]
__global__ void elr_feat_kernel(const float* __restrict__ feat, const float* __restrict__ al,
                                const float* __restrict__ ar, float* __restrict__ el,
                                float* __restrict__ er, int RH) {
    int idx = blockIdx.x * blockDim.x + threadIdx.x;
    if (idx >= RH) return;
    int h = idx & (HEADS - 1);
    const float* fp = feat + (size_t)idx * HIDDEN;
    float sl = 0.f, sr = 0.f;
    for (int f = 0; f < HIDDEN; ++f) {
        float v = fp[f];
        sl = fmaf(v, al[h * HIDDEN + f], sl);
        sr = fmaf(v, ar[h * HIDDEN + f], sr);
    }
    el[idx] = sl;
    er[idx] = sr;
}

// layers 2/3: el[r,h] = X[r,:]·aleff[h,:]  (X: [R,64])
__global__ void elr_in_kernel(const float* __restrict__ X, const float* __restrict__ aleff,
                              const float* __restrict__ areff, float* __restrict__ el,
                              float* __restrict__ er, int R) {
    int idx = blockIdx.x * blockDim.x + threadIdx.x;
    if (idx >= R * HEADS) return;
    int h = idx & (HEADS - 1);
    int r = idx >> 3;
    const float* x = X + (size_t)r * 64;
    float sl = 0.f, sr = 0.f;
    for (int k = 0; k < 64; ++k) {
        float v = x[k];
        sl = fmaf(v, aleff[h * 64 + k], sl);
        sr = fmaf(v, areff[h * 64 + k], sr);
    }
    el[idx] = sl;
    er[idx] = sr;
}

__device__ __forceinline__ float gelu_exact(float v) {
    return 0.5f * v * (1.0f + erff(v * 0.70710678118654752440f));
}

// ---------------- layer-1 aggregation (feat space), writes gelu(out) = h1 ----------------
__global__ __launch_bounds__(256) void agg_feat_l1(
    const float* __restrict__ feat,  // [N*8, 64]
    const float* __restrict__ el, const float* __restrict__ er,  // [N*8]
    const float* __restrict__ bias,  // [8*64]
    const int* __restrict__ row_ptr, const int* __restrict__ edge_idx,
    const int* __restrict__ src, float* __restrict__ out)  // [N*8,64]
{
    int n = blockIdx.x;
    int r0 = row_ptr[n], deg = row_ptr[n + 1] - r0;
    int t = threadIdx.x;
    __shared__ float m_s[8], den_s[8], er_s[8];
    __shared__ int src_s[256];
    __shared__ float w_s[256 * 8];
    if (t < 8) er_s[t] = er[n * 8 + t];
    float m_run = -1e30f, den_run = 0.f;
    for (int base = 0; base < deg; base += 256) {
        int cnt = min(deg - base, 256);
        __syncthreads();
        if (t < cnt) src_s[t] = src[edge_idx[r0 + base + t]];
        __syncthreads();
        if (t < 8) {
            for (int i = 0; i < cnt; ++i) {
                float e = el[src_s[i] * 8 + t] + er_s[t];
                e = e > 0.f ? e : 0.2f * e;
                float mn = fmaxf(m_run, e);
                den_run = den_run * __expf(m_run - mn) + __expf(e - mn);
                m_run = mn;
            }
        }
    }
    if (t < 8) { m_s[t] = m_run; den_s[t] = den_run; }
    float acc0 = 0.f, acc1 = 0.f;
    int h0 = t >> 6, f = t & 63;
    for (int base = 0; base < deg; base += 256) {
        int cnt = min(deg - base, 256);
        __syncthreads();
        if (t < cnt) src_s[t] = src[edge_idx[r0 + base + t]];
        __syncthreads();
        for (int j = t; j < cnt * 8; j += 256) {
            int i = j >> 3, h = j & 7;
            float e = el[src_s[i] * 8 + h] + er_s[h];
            e = e > 0.f ? e : 0.2f * e;
            w_s[j] = __expf(e - m_s[h]);
        }
        __syncthreads();
        for (int i = 0; i < cnt; ++i) {
            int s = src_s[i];
            acc0 = fmaf(w_s[i * 8 + h0],     feat[((size_t)s * 8 + h0) * 64 + f], acc0);
            acc1 = fmaf(w_s[i * 8 + h0 + 4], feat[((size_t)s * 8 + h0 + 4) * 64 + f], acc1);
        }
    }
    __syncthreads();
    float v0 = (deg ? acc0 / den_s[h0] : 0.f) + bias[t];
    float v1 = (deg ? acc1 / den_s[h0 + 4] : 0.f) + bias[t + 256];
    out[(size_t)n * 512 + t] = gelu_exact(v0);
    out[(size_t)n * 512 + t + 256] = gelu_exact(v1);
}

// ---------------- layers 2/3: input-space aggregation + fused block-diag transform ----------------
template <int FOUT, bool GELU, int P, int PSHIFT>
__global__ __launch_bounds__(256) void agg_fused(
    const float* __restrict__ X,   // [N*P, 64]
    const float* __restrict__ el, const float* __restrict__ er,  // [N*P*8]
    const float* __restrict__ W,   // [64, 8*FOUT]
    const float* __restrict__ bias,  // [8*FOUT]
    const int* __restrict__ row_ptr, const int* __restrict__ edge_idx,
    const int* __restrict__ src, float* __restrict__ out)  // [N*P, 8*FOUT]
{
    int np = blockIdx.x;
    int n = np >> PSHIFT, p = np & (P - 1);
    int r0 = row_ptr[n], deg = row_ptr[n + 1] - r0;
    int t = threadIdx.x;
    __shared__ float m_s[8], den_s[8], er_s[8];
    __shared__ int src_s[256];
    __shared__ float w_s[256 * 8];
    __shared__ float acc_s[8][65];
    if (t < 8) er_s[t] = er[(size_t)np * 8 + t];
    float m_run = -1e30f, den_run = 0.f;
    for (int base = 0; base < deg; base += 256) {
        int cnt = min(deg - base, 256);
        __syncthreads();
        if (t < cnt) src_s[t] = src[edge_idx[r0 + base + t]];
        __syncthreads();
        if (t < 8) {
            for (int i = 0; i < cnt; ++i) {
                float e = el[((size_t)src_s[i] * P + p) * 8 + t] + er_s[t];
                e = e > 0.f ? e : 0.2f * e;
                float mn = fmaxf(m_run, e);
                den_run = den_run * __expf(m_run - mn) + __expf(e - mn);
                m_run = mn;
            }
        }
    }
    if (t < 8) { m_s[t] = m_run; den_s[t] = den_run; }
    float acc0 = 0.f, acc1 = 0.f;
    int h0 = t >> 6, k = t & 63;
    for (int base = 0; base < deg; base += 256) {
        int cnt = min(deg - base, 256);
        __syncthreads();
        if (t < cnt) src_s[t] = src[edge_idx[r0 + base + t]];
        __syncthreads();
        for (int j = t; j < cnt * 8; j += 256) {
            int i = j >> 3, h = j & 7;
            float e = el[((size_t)src_s[i] * P + p) * 8 + h] + er_s[h];
            e = e > 0.f ? e : 0.2f * e;
            w_s[j] = __expf(e - m_s[h]);
        }
        __syncthreads();
        for (int i = 0; i < cnt; ++i) {
            int s = src_s[i];
            float xv = X[((size_t)s * P + p) * 64 + k];
            acc0 = fmaf(w_s[i * 8 + h0], xv, acc0);
            acc1 = fmaf(w_s[i * 8 + h0 + 4], xv, acc1);
        }
    }
    __syncthreads();
    float i0 = deg ? 1.f / den_s[h0] : 0.f;
    float i1 = deg ? 1.f / den_s[h0 + 4] : 0.f;
    acc_s[h0][k] = acc0 * i0;
    acc_s[h0 + 4][k] = acc1 * i1;
    __syncthreads();
    const int TOT = 8 * FOUT;
    for (int idx = t; idx < TOT; idx += 256) {
        int h = idx / FOUT;
        float val = bias[idx];
        #pragma unroll 4
        for (int k2 = 0; k2 < 64; ++k2)
            val = fmaf(acc_s[h][k2], W[(size_t)k2 * TOT + idx], val);
        if (GELU) val = gelu_exact(val);
        out[(size_t)np * TOT + idx] = val;
    }
}

// ---------------- launch ----------------

extern "C" void kernel_launch(void* const* d_in, const int* in_sizes, int n_in,
                              void* d_out, int out_size, void* d_ws, size_t ws_size,
                              hipStream_t stream) {
    const float* node = (const float*)d_in[0];
    const int* src = (const int*)d_in[1];
    const int* dst = (const int*)d_in[2];
    const float* W1 = (const float*)d_in[3];
    const float* al1 = (const float*)d_in[4];
    const float* ar1 = (const float*)d_in[5];
    const float* b1 = (const float*)d_in[6];
    const float* W2 = (const float*)d_in[7];
    const float* al2 = (const float*)d_in[8];
    const float* ar2 = (const float*)d_in[9];
    const float* b2 = (const float*)d_in[10];
    const float* W3 = (const float*)d_in[11];
    const float* al3 = (const float*)d_in[12];
    const float* ar3 = (const float*)d_in[13];
    const float* b3 = (const float*)d_in[14];
    float* out = (float*)d_out;

    char* ws = (char*)d_ws;
    size_t off = 0;
    auto alloc = [&](size_t nb) -> char* {
        char* q = ws + off;
        off += (nb + 255) & ~(size_t)255;
        return q;
    };
    int* counts   = (int*)alloc((N_NODES + 1) * sizeof(int));
    int* row_ptr  = (int*)alloc((N_NODES + 1) * sizeof(int));
    int* rnk      = (int*)alloc(N_EDGES * sizeof(int));
    int* edge_idx = (int*)alloc(N_EDGES * sizeof(int));
    float* feat1  = (float*)alloc((size_t)N_NODES * 8 * 64 * 4);   // 3 MB
    float* el1    = (float*)alloc((size_t)N_NODES * 8 * 4);
    float* er1    = (float*)alloc((size_t)N_NODES * 8 * 4);
    float* h1     = (float*)alloc((size_t)N_NODES * 8 * 64 * 4);   // 3 MB
    float* aleff2 = (float*)alloc(8 * 64 * 4);
    float* areff2 = (float*)alloc(8 * 64 * 4);
    float* el2    = (float*)alloc((size_t)N_NODES * 8 * 8 * 4);
    float* er2    = (float*)alloc((size_t)N_NODES * 8 * 8 * 4);
    float* h2     = (float*)alloc((size_t)N_NODES * 64 * 64 * 4);  // 24.6 MB
    float* aleff3 = (float*)alloc(8 * 64 * 4);
    float* areff3 = (float*)alloc(8 * 64 * 4);
    float* el3    = (float*)alloc((size_t)N_NODES * 64 * 8 * 4);
    float* er3    = (float*)alloc((size_t)N_NODES * 64 * 8 * 4);

    // CSR build (deterministic)
    zero_counts_kernel<<<(N_NODES + 256) / 256, 256, 0, stream>>>(counts);
    hist_kernel<<<(N_EDGES + 255) / 256, 256, 0, stream>>>(dst, counts);
    rank_kernel<<<(N_EDGES + 255) / 256, 256, 0, stream>>>(dst, rnk);
    scan_kernel<<<1, 256, 0, stream>>>(counts, row_ptr);
    scatter_kernel<<<(N_EDGES + 255) / 256, 256, 0, stream>>>(dst, rnk, row_ptr, edge_idx);

    // effective attention vectors for layers 2/3
    att_eff_kernel<<<2, 256, 0, stream>>>(W2, al2, aleff2, 64, HIDDEN);
    att_eff_kernel<<<2, 256, 0, stream>>>(W2, ar2, areff2, 64, HIDDEN);
    att_eff_kernel<<<2, 256, 0, stream>>>(W3, al3, aleff3, 64, OUT_FEAT);
    att_eff_kernel<<<2, 256, 0, stream>>>(W3, ar3, areff3, 64, OUT_FEAT);

    // ---- layer 1 ----
    dim3 g1(512 / BN, (N_NODES + BM - 1) / BM);
    gemm_f32<<<g1, 256, 0, stream>>>(node, W1, feat1, N_NODES, 512, IN_FEAT);
    elr_feat_kernel<<<(N_NODES * 8 + 255) / 256, 256, 0, stream>>>(feat1, al1, ar1, el1, er1, N_NODES * 8);
    agg_feat_l1<<<N_NODES, 256, 0, stream>>>(feat1, el1, er1, b1, row_ptr, edge_idx, src, h1);

    // ---- layer 2 ----
    elr_in_kernel<<<(N_NODES * 8 * 8 + 255) / 256, 256, 0, stream>>>(h1, aleff2, areff2, el2, er2, N_NODES * 8);
    agg_fused<64, true, 8, 3><<<N_NODES * 8, 256, 0, stream>>>(h1, el2, er2, W2, b2, row_ptr, edge_idx, src, h2);

    // ---- layer 3 ----
    elr_in_kernel<<<(N_NODES * 64 * 8 + 255) / 256, 256, 0, stream>>>(h2, aleff3, areff3, el3, er3, N_NODES * 64);
    agg_fused<32, false, 64, 6><<<N_NODES * 64, 256, 0, stream>>>(h2, el3, er3, W3, b3, row_ptr, edge_idx, src, out);
}

// Round 2
// 725.762 us; speedup vs baseline: 1.4571x; 1.4571x over previous
//
#include <hip/hip_runtime.h>
#include <math.h>

#define N_NODES 1500
#define N_EDGES 12000
#define IN_FEAT 512
#define HIDDEN 64
#define OUT_FEAT 32
#define HEADS 8

// ---------------- graph preprocessing (deterministic CSR by dst) ----------------

__global__ void zero_counts_kernel(int* counts) {
    int i = blockIdx.x * blockDim.x + threadIdx.x;
    if (i < N_NODES + 1) counts[i] = 0;
}

__global__ void hist_kernel(const int* __restrict__ dst, int* __restrict__ counts) {
    int e = blockIdx.x * blockDim.x + threadIdx.x;
    if (e < N_EDGES) atomicAdd(&counts[dst[e]], 1);
}

__global__ void scan_kernel(const int* __restrict__ counts, int* __restrict__ row_ptr) {
    __shared__ int part[256];
    int t = threadIdx.x;
    const int CH = (N_NODES + 255) / 256; // 6
    int base = t * CH;
    int loc[8];
    int s = 0;
    for (int i = 0; i < CH; ++i) {
        int idx = base + i;
        int v = (idx < N_NODES) ? counts[idx] : 0;
        loc[i] = s;
        s += v;
    }
    part[t] = s;
    __syncthreads();
    if (t == 0) {
        int a = 0;
        for (int i = 0; i < 256; ++i) { int v = part[i]; part[i] = a; a += v; }
        row_ptr[N_NODES] = a;
    }
    __syncthreads();
    int p0 = part[t];
    for (int i = 0; i < CH; ++i) {
        int idx = base + i;
        if (idx < N_NODES) row_ptr[idx] = p0 + loc[i];
    }
}

// wave-per-node stable CSR build: deterministic, replaces O(E^2) rank kernel.
__global__ void build_csr_kernel(const int* __restrict__ dst, const int* __restrict__ row_ptr,
                                 int* __restrict__ edge_idx) {
    int wid = (blockIdx.x * blockDim.x + threadIdx.x) >> 6;
    int lane = threadIdx.x & 63;
    if (wid >= N_NODES) return;
    int pos = row_ptr[wid];
    for (int base = 0; base < N_EDGES; base += 64) {
        int e = base + lane;
        bool hit = (e < N_EDGES) && (dst[e] == wid);
        unsigned long long m = __ballot(hit);
        if (hit) {
            int r = __popcll(m & ((1ull << lane) - 1ull));
            edge_idx[pos + r] = e;
        }
        pos += __popcll(m);
    }
}

// ---------------- f32 tiled GEMM (layer 1 only): C[M,N] = A[M,K] @ B[K,N] ----------------

#define BM 64
#define BN 64
#define BK 16

__global__ __launch_bounds__(256) void gemm_f32(const float* __restrict__ A,
                                                const float* __restrict__ B,
                                                float* __restrict__ C,
                                                int M, int N, int K) {
    __shared__ float As[BK][BM + 4];
    __shared__ float Bs[BK][BN + 4];
    int t = threadIdx.x;
    int col0 = blockIdx.x * BN, row0 = blockIdx.y * BM;
    int tx = t & 15, ty = t >> 4;
    float acc[4][4] = {};
    for (int k0 = 0; k0 < K; k0 += BK) {
        {
            int k = t & 15, m0 = t >> 4;
            #pragma unroll
            for (int i = 0; i < 4; ++i) {
                int m = m0 + 16 * i;
                int gr = row0 + m;
                As[k][m] = (gr < M) ? A[(size_t)gr * K + k0 + k] : 0.0f;
            }
        }
        {
            int n = t & 63, k4 = t >> 6;
            #pragma unroll
            for (int i = 0; i < 4; ++i) {
                int k = k4 * 4 + i;
                Bs[k][n] = B[(size_t)(k0 + k) * N + col0 + n];
            }
        }
        __syncthreads();
        #pragma unroll
        for (int kk = 0; kk < BK; ++kk) {
            float4 a4 = *(const float4*)&As[kk][ty * 4];
            float4 b4 = *(const float4*)&Bs[kk][tx * 4];
            float av[4] = {a4.x, a4.y, a4.z, a4.w};
            float bv[4] = {b4.x, b4.y, b4.z, b4.w};
            #pragma unroll
            for (int i = 0; i < 4; ++i)
                #pragma unroll
                for (int j = 0; j < 4; ++j)
                    acc[i][j] = fmaf(av[i], bv[j], acc[i][j]);
        }
        __syncthreads();
    }
    #pragma unroll
    for (int i = 0; i < 4; ++i) {
        int gr = row0 + ty * 4 + i;
        if (gr < M) {
            float4 v = make_float4(acc[i][0], acc[i][1], acc[i][2], acc[i][3]);
            *(float4*)&C[(size_t)gr * N + col0 + tx * 4] = v;
        }
    }
}

// ---------------- attention-vector transforms ----------------

// out[h,k] = sum_f W[k, h*Fo+f] * a[h,f]
__global__ void att_eff_kernel(const float* __restrict__ W, const float* __restrict__ a,
                               float* __restrict__ out, int K, int Fo) {
    int idx = blockIdx.x * blockDim.x + threadIdx.x;
    if (idx >= HEADS * K) return;
    int h = idx / K, k = idx - h * K;
    float s = 0.f;
    for (int f = 0; f < Fo; ++f)
        s = fmaf(W[(size_t)k * (HEADS * Fo) + h * Fo + f], a[h * Fo + f], s);
    out[idx] = s;
}

// Wt[c][k] = W[k][c]  (for float4 row reads in the fused transform)
__global__ void transpose_w_kernel(const float* __restrict__ W, float* __restrict__ Wt,
                                   int K, int TOT) {
    int idx = blockIdx.x * blockDim.x + threadIdx.x;
    if (idx >= K * TOT) return;
    int k = idx / TOT, c = idx - k * TOT;
    Wt[(size_t)c * K + k] = W[idx];
}

// layer-1: el/er per (n,h) row of feat1 [N*8, 64]
__global__ void elr_feat_kernel(const float* __restrict__ feat, const float* __restrict__ al,
                                const float* __restrict__ ar, float* __restrict__ el,
                                float* __restrict__ er, int RH) {
    int idx = blockIdx.x * blockDim.x + threadIdx.x;
    if (idx >= RH) return;
    int h = idx & (HEADS - 1);
    const float* fp = feat + (size_t)idx * HIDDEN;
    float sl = 0.f, sr = 0.f;
    for (int f = 0; f < HIDDEN; ++f) {
        float v = fp[f];
        sl = fmaf(v, al[h * HIDDEN + f], sl);
        sr = fmaf(v, ar[h * HIDDEN + f], sr);
    }
    el[idx] = sl;
    er[idx] = sr;
}

// layers 2/3: el[r,h] = X[r,:]·aleff[h,:]  (X: [R,64])
__global__ void elr_in_kernel(const float* __restrict__ X, const float* __restrict__ aleff,
                              const float* __restrict__ areff, float* __restrict__ el,
                              float* __restrict__ er, int R) {
    int idx = blockIdx.x * blockDim.x + threadIdx.x;
    if (idx >= R * HEADS) return;
    int h = idx & (HEADS - 1);
    int r = idx >> 3;
    const float* x = X + (size_t)r * 64;
    float sl = 0.f, sr = 0.f;
    for (int k = 0; k < 64; ++k) {
        float v = x[k];
        sl = fmaf(v, aleff[h * 64 + k], sl);
        sr = fmaf(v, areff[h * 64 + k], sr);
    }
    el[idx] = sl;
    er[idx] = sr;
}

__device__ __forceinline__ float gelu_exact(float v) {
    return 0.5f * v * (1.0f + erff(v * 0.70710678118654752440f));
}

// ---------------- layer-1 aggregation (feat space), writes gelu(out) = h1 ----------------
__global__ __launch_bounds__(256) void agg_feat_l1(
    const float* __restrict__ feat,
    const float* __restrict__ el, const float* __restrict__ er,
    const float* __restrict__ bias,
    const int* __restrict__ row_ptr, const int* __restrict__ edge_idx,
    const int* __restrict__ src, float* __restrict__ out)
{
    int n = blockIdx.x;
    int r0 = row_ptr[n], deg = row_ptr[n + 1] - r0;
    int t = threadIdx.x;
    __shared__ float m_s[8], den_s[8], er_s[8];
    __shared__ int src_s[256];
    __shared__ float w_s[256 * 8];
    if (t < 8) er_s[t] = er[n * 8 + t];
    float m_run = -1e30f, den_run = 0.f;
    for (int base = 0; base < deg; base += 256) {
        int cnt = min(deg - base, 256);
        __syncthreads();
        if (t < cnt) src_s[t] = src[edge_idx[r0 + base + t]];
        __syncthreads();
        if (t < 8) {
            for (int i = 0; i < cnt; ++i) {
                float e = el[src_s[i] * 8 + t] + er_s[t];
                e = e > 0.f ? e : 0.2f * e;
                float mn = fmaxf(m_run, e);
                den_run = den_run * __expf(m_run - mn) + __expf(e - mn);
                m_run = mn;
            }
        }
    }
    if (t < 8) { m_s[t] = m_run; den_s[t] = den_run; }
    float acc0 = 0.f, acc1 = 0.f;
    int h0 = t >> 6, f = t & 63;
    for (int base = 0; base < deg; base += 256) {
        int cnt = min(deg - base, 256);
        __syncthreads();
        if (t < cnt) src_s[t] = src[edge_idx[r0 + base + t]];
        __syncthreads();
        for (int j = t; j < cnt * 8; j += 256) {
            int i = j >> 3, h = j & 7;
            float e = el[src_s[i] * 8 + h] + er_s[h];
            e = e > 0.f ? e : 0.2f * e;
            w_s[j] = __expf(e - m_s[h]);
        }
        __syncthreads();
        for (int i = 0; i < cnt; ++i) {
            int s = src_s[i];
            acc0 = fmaf(w_s[i * 8 + h0],     feat[((size_t)s * 8 + h0) * 64 + f], acc0);
            acc1 = fmaf(w_s[i * 8 + h0 + 4], feat[((size_t)s * 8 + h0 + 4) * 64 + f], acc1);
        }
    }
    __syncthreads();
    float v0 = (deg ? acc0 / den_s[h0] : 0.f) + bias[t];
    float v1 = (deg ? acc1 / den_s[h0 + 4] : 0.f) + bias[t + 256];
    out[(size_t)n * 512 + t] = gelu_exact(v0);
    out[(size_t)n * 512 + t + 256] = gelu_exact(v1);
}

// ---------------- layers 2/3: multi-p aggregation + fused block-diag transform ----------------
// One block handles PGRP prefix values of one node. W passed TRANSPOSED: Wt[TOT][64].
template <int FOUT, bool GELU, int P, int PGRP>
__global__ __launch_bounds__(256) void agg_fused2(
    const float* __restrict__ X,     // [N*P, 64]
    const float* __restrict__ el, const float* __restrict__ er,  // [N*P*8]
    const float* __restrict__ Wt,    // [8*FOUT, 64] (transposed)
    const float* __restrict__ bias,  // [8*FOUT]
    const int* __restrict__ row_ptr, const int* __restrict__ edge_idx,
    const int* __restrict__ src, float* __restrict__ out)  // [N*P, 8*FOUT]
{
    constexpr int GRPS = P / PGRP;
    constexpr int TOT = 8 * FOUT;
    int nb = blockIdx.x;
    int n = nb / GRPS;
    int pg = nb - n * GRPS;
    int p0 = pg * PGRP;
    int r0 = row_ptr[n], deg = row_ptr[n + 1] - r0;
    int t = threadIdx.x;

    __shared__ float m_s[PGRP * 8], den_s[PGRP * 8], er_s[PGRP * 8];
    __shared__ int src_s[256];
    __shared__ float w_s[256 * 8];
    __shared__ float acc_s[PGRP][8][68];   // 68-stride: float4-aligned rows

    if (t < PGRP * 8) er_s[t] = er[((size_t)n * P + p0) * 8 + t];

    // phase 1: online softmax stats for all (p,h) in group (threads 0..PGRP*8-1)
    float m_run = -1e30f, den_run = 0.f;
    for (int base = 0; base < deg; base += 256) {
        int cnt = min(deg - base, 256);
        __syncthreads();
        if (t < cnt) src_s[t] = src[edge_idx[r0 + base + t]];
        __syncthreads();
        if (t < PGRP * 8) {
            for (int i = 0; i < cnt; ++i) {
                float e = el[((size_t)src_s[i] * P + p0) * 8 + t] + er_s[t];
                e = e > 0.f ? e : 0.2f * e;
                float mn = fmaxf(m_run, e);
                den_run = den_run * __expf(m_run - mn) + __expf(e - mn);
                m_run = mn;
            }
        }
    }
    if (t < PGRP * 8) { m_s[t] = m_run; den_s[t] = den_run; }
    __syncthreads();

    // phase 2: per-p aggregation in input space
    int h0 = t >> 6, k = t & 63;
    for (int pl = 0; pl < PGRP; ++pl) {
        float acc0 = 0.f, acc1 = 0.f;
        for (int base = 0; base < deg; base += 256) {
            int cnt = min(deg - base, 256);
            __syncthreads();
            if (t < cnt) src_s[t] = src[edge_idx[r0 + base + t]];
            __syncthreads();
            for (int j = t; j < cnt * 8; j += 256) {
                int i = j >> 3, h = j & 7;
                float e = el[((size_t)src_s[i] * P + p0 + pl) * 8 + h] + er_s[pl * 8 + h];
                e = e > 0.f ? e : 0.2f * e;
                w_s[j] = __expf(e - m_s[pl * 8 + h]);
            }
            __syncthreads();
            for (int i = 0; i < cnt; ++i) {
                int s = src_s[i];
                float xv = X[((size_t)s * P + p0 + pl) * 64 + k];
                acc0 = fmaf(w_s[i * 8 + h0], xv, acc0);
                acc1 = fmaf(w_s[i * 8 + h0 + 4], xv, acc1);
            }
        }
        float i0 = deg ? 1.f / den_s[pl * 8 + h0] : 0.f;
        float i1 = deg ? 1.f / den_s[pl * 8 + h0 + 4] : 0.f;
        acc_s[pl][h0][k] = acc0 * i0;
        acc_s[pl][h0 + 4][k] = acc1 * i1;
    }
    __syncthreads();

    // phase 3: block-diagonal transform, register-blocked over p.
    // Each W element is loaded once and used for all PGRP prefix values.
    for (int idx = t; idx < TOT; idx += 256) {
        int h = idx / FOUT;
        float val[PGRP];
        #pragma unroll
        for (int pl = 0; pl < PGRP; ++pl) val[pl] = bias[idx];
        const float* wrow = Wt + (size_t)idx * 64;
        #pragma unroll
        for (int kg = 0; kg < 16; ++kg) {
            float4 w4 = *(const float4*)(wrow + kg * 4);
            #pragma unroll
            for (int pl = 0; pl < PGRP; ++pl) {
                float4 a4 = *(const float4*)&acc_s[pl][h][kg * 4];
                val[pl] = fmaf(a4.x, w4.x, val[pl]);
                val[pl] = fmaf(a4.y, w4.y, val[pl]);
                val[pl] = fmaf(a4.z, w4.z, val[pl]);
                val[pl] = fmaf(a4.w, w4.w, val[pl]);
            }
        }
        #pragma unroll
        for (int pl = 0; pl < PGRP; ++pl) {
            float v = val[pl];
            if (GELU) v = gelu_exact(v);
            out[((size_t)n * P + p0 + pl) * TOT + idx] = v;
        }
    }
}

// ---------------- launch ----------------

extern "C" void kernel_launch(void* const* d_in, const int* in_sizes, int n_in,
                              void* d_out, int out_size, void* d_ws, size_t ws_size,
                              hipStream_t stream) {
    const float* node = (const float*)d_in[0];
    const int* src = (const int*)d_in[1];
    const int* dst = (const int*)d_in[2];
    const float* W1 = (const float*)d_in[3];
    const float* al1 = (const float*)d_in[4];
    const float* ar1 = (const float*)d_in[5];
    const float* b1 = (const float*)d_in[6];
    const float* W2 = (const float*)d_in[7];
    const float* al2 = (const float*)d_in[8];
    const float* ar2 = (const float*)d_in[9];
    const float* b2 = (const float*)d_in[10];
    const float* W3 = (const float*)d_in[11];
    const float* al3 = (const float*)d_in[12];
    const float* ar3 = (const float*)d_in[13];
    const float* b3 = (const float*)d_in[14];
    float* out = (float*)d_out;

    char* ws = (char*)d_ws;
    size_t off = 0;
    auto alloc = [&](size_t nb) -> char* {
        char* q = ws + off;
        off += (nb + 255) & ~(size_t)255;
        return q;
    };
    int* counts   = (int*)alloc((N_NODES + 1) * sizeof(int));
    int* row_ptr  = (int*)alloc((N_NODES + 1) * sizeof(int));
    int* edge_idx = (int*)alloc(N_EDGES * sizeof(int));
    float* feat1  = (float*)alloc((size_t)N_NODES * 8 * 64 * 4);
    float* el1    = (float*)alloc((size_t)N_NODES * 8 * 4);
    float* er1    = (float*)alloc((size_t)N_NODES * 8 * 4);
    float* h1     = (float*)alloc((size_t)N_NODES * 8 * 64 * 4);
    float* aleff2 = (float*)alloc(8 * 64 * 4);
    float* areff2 = (float*)alloc(8 * 64 * 4);
    float* el2    = (float*)alloc((size_t)N_NODES * 8 * 8 * 4);
    float* er2    = (float*)alloc((size_t)N_NODES * 8 * 8 * 4);
    float* h2     = (float*)alloc((size_t)N_NODES * 64 * 64 * 4);
    float* aleff3 = (float*)alloc(8 * 64 * 4);
    float* areff3 = (float*)alloc(8 * 64 * 4);
    float* el3    = (float*)alloc((size_t)N_NODES * 64 * 8 * 4);
    float* er3    = (float*)alloc((size_t)N_NODES * 64 * 8 * 4);
    float* W2t    = (float*)alloc((size_t)64 * 512 * 4);
    float* W3t    = (float*)alloc((size_t)64 * 256 * 4);

    // CSR build (deterministic)
    zero_counts_kernel<<<(N_NODES + 256) / 256, 256, 0, stream>>>(counts);
    hist_kernel<<<(N_EDGES + 255) / 256, 256, 0, stream>>>(dst, counts);
    scan_kernel<<<1, 256, 0, stream>>>(counts, row_ptr);
    build_csr_kernel<<<(N_NODES * 64 + 255) / 256, 256, 0, stream>>>(dst, row_ptr, edge_idx);

    // effective attention vectors + transposed weights for layers 2/3
    att_eff_kernel<<<2, 256, 0, stream>>>(W2, al2, aleff2, 64, HIDDEN);
    att_eff_kernel<<<2, 256, 0, stream>>>(W2, ar2, areff2, 64, HIDDEN);
    att_eff_kernel<<<2, 256, 0, stream>>>(W3, al3, aleff3, 64, OUT_FEAT);
    att_eff_kernel<<<2, 256, 0, stream>>>(W3, ar3, areff3, 64, OUT_FEAT);
    transpose_w_kernel<<<(64 * 512 + 255) / 256, 256, 0, stream>>>(W2, W2t, 64, 512);
    transpose_w_kernel<<<(64 * 256 + 255) / 256, 256, 0, stream>>>(W3, W3t, 64, 256);

    // ---- layer 1 ----
    dim3 g1(512 / BN, (N_NODES + BM - 1) / BM);
    gemm_f32<<<g1, 256, 0, stream>>>(node, W1, feat1, N_NODES, 512, IN_FEAT);
    elr_feat_kernel<<<(N_NODES * 8 + 255) / 256, 256, 0, stream>>>(feat1, al1, ar1, el1, er1, N_NODES * 8);
    agg_feat_l1<<<N_NODES, 256, 0, stream>>>(feat1, el1, er1, b1, row_ptr, edge_idx, src, h1);

    // ---- layer 2 ----  (P=8, PGRP=8 -> 1500 blocks)
    elr_in_kernel<<<(N_NODES * 8 * 8 + 255) / 256, 256, 0, stream>>>(h1, aleff2, areff2, el2, er2, N_NODES * 8);
    agg_fused2<64, true, 8, 8><<<N_NODES, 256, 0, stream>>>(h1, el2, er2, W2t, b2, row_ptr, edge_idx, src, h2);

    // ---- layer 3 ----  (P=64, PGRP=8 -> 12000 blocks)
    elr_in_kernel<<<(N_NODES * 64 * 8 + 255) / 256, 256, 0, stream>>>(h2, aleff3, areff3, el3, er3, N_NODES * 64);
    agg_fused2<32, false, 64, 8><<<N_NODES * 8, 256, 0, stream>>>(h2, el3, er3, W3t, b3, row_ptr, edge_idx, src, out);
}

// Round 3
// 375.112 us; speedup vs baseline: 2.8192x; 1.9348x over previous
//
#include <hip/hip_runtime.h>
#include <math.h>

#define N_NODES 1500
#define N_EDGES 12000
#define IN_FEAT 512
#define HIDDEN 64
#define OUT_FEAT 32
#define HEADS 8

// ---------------- fused prep: zero counts + att-eff vectors + W reshuffle ----------------
// W4t layout: W4t[(kg*TOT + c)*4 + j] = W[(kg*4+j)*TOT + c]  (kg<16, j<4, c<TOT)

__global__ void prep_kernel(const float* __restrict__ W2, const float* __restrict__ al2,
                            const float* __restrict__ ar2,
                            const float* __restrict__ W3, const float* __restrict__ al3,
                            const float* __restrict__ ar3,
                            float* __restrict__ aleff2, float* __restrict__ areff2,
                            float* __restrict__ aleff3, float* __restrict__ areff3,
                            float* __restrict__ W4t2, float* __restrict__ W4t3,
                            int* __restrict__ counts) {
    int i = blockIdx.x * blockDim.x + threadIdx.x;
    if (i < 1536) {
        if (i < N_NODES + 1) counts[i] = 0;
        return;
    }
    i -= 1536;
    if (i < 1024) {  // aleff2 / areff2: [h][64]
        int lr = i >> 9; i &= 511;
        int h = i >> 6, k = i & 63;
        const float* a = lr ? ar2 : al2;
        float s = 0.f;
        for (int f = 0; f < 64; ++f)
            s = fmaf(W2[(size_t)k * 512 + h * 64 + f], a[h * 64 + f], s);
        (lr ? areff2 : aleff2)[h * 64 + k] = s;
        return;
    }
    i -= 1024;
    if (i < 1024) {  // aleff3 / areff3
        int lr = i >> 9; i &= 511;
        int h = i >> 6, k = i & 63;
        const float* a = lr ? ar3 : al3;
        float s = 0.f;
        for (int f = 0; f < 32; ++f)
            s = fmaf(W3[(size_t)k * 256 + h * 32 + f], a[h * 32 + f], s);
        (lr ? areff3 : aleff3)[h * 64 + k] = s;
        return;
    }
    i -= 1024;
    if (i < 16 * 512 * 4) {  // W4t2 (TOT=512)
        int kg = i >> 11, rem = i & 2047;
        int c = rem >> 2, j = rem & 3;
        W4t2[i] = W2[(size_t)(kg * 4 + j) * 512 + c];
        return;
    }
    i -= 16 * 512 * 4;
    if (i < 16 * 256 * 4) {  // W4t3 (TOT=256)
        int kg = i >> 10, rem = i & 1023;
        int c = rem >> 2, j = rem & 3;
        W4t3[i] = W3[(size_t)(kg * 4 + j) * 256 + c];
    }
}

__global__ void hist_kernel(const int* __restrict__ dst, int* __restrict__ counts) {
    int e = blockIdx.x * blockDim.x + threadIdx.x;
    if (e < N_EDGES) atomicAdd(&counts[dst[e]], 1);
}

__global__ void scan_kernel(const int* __restrict__ counts, int* __restrict__ row_ptr) {
    __shared__ int part[256];
    int t = threadIdx.x;
    const int CH = (N_NODES + 255) / 256;
    int base = t * CH;
    int loc[8];
    int s = 0;
    for (int i = 0; i < CH; ++i) {
        int idx = base + i;
        int v = (idx < N_NODES) ? counts[idx] : 0;
        loc[i] = s;
        s += v;
    }
    part[t] = s;
    __syncthreads();
    if (t == 0) {
        int a = 0;
        for (int i = 0; i < 256; ++i) { int v = part[i]; part[i] = a; a += v; }
        row_ptr[N_NODES] = a;
    }
    __syncthreads();
    int p0 = part[t];
    for (int i = 0; i < CH; ++i) {
        int idx = base + i;
        if (idx < N_NODES) row_ptr[idx] = p0 + loc[i];
    }
}

// wave-per-node stable CSR build; stores SRC NODE ID directly (csr_src).
__global__ void build_csr_kernel(const int* __restrict__ dst, const int* __restrict__ src,
                                 const int* __restrict__ row_ptr, int* __restrict__ csr_src) {
    int wid = (blockIdx.x * blockDim.x + threadIdx.x) >> 6;
    int lane = threadIdx.x & 63;
    if (wid >= N_NODES) return;
    int pos = row_ptr[wid];
    for (int base = 0; base < N_EDGES; base += 64) {
        int e = base + lane;
        bool hit = (e < N_EDGES) && (dst[e] == wid);
        unsigned long long m = __ballot(hit);
        if (hit) {
            int r = __popcll(m & ((1ull << lane) - 1ull));
            csr_src[pos + r] = src[e];
        }
        pos += __popcll(m);
    }
}

// ---------------- f32 tiled GEMM (layer 1): BK=32, register prefetch ----------------

#define BM 64
#define BN 64
#define BK2 32

__global__ __launch_bounds__(256) void gemm_f32(const float* __restrict__ A,
                                                const float* __restrict__ B,
                                                float* __restrict__ C,
                                                int M, int N, int K) {
    __shared__ float As[BK2][BM + 4];
    __shared__ float Bs[BK2][BN + 4];
    int t = threadIdx.x;
    int col0 = blockIdx.x * BN, row0 = blockIdx.y * BM;
    int tx = t & 15, ty = t >> 4;
    int am = t >> 3, ak = (t & 7) * 4;     // A staging: rows am, am+32; k = ak..ak+3
    int bk = t >> 4, bn = (t & 15) * 4;    // B staging: k rows bk, bk+16; cols bn..bn+3
    float4 pa[2], pb[2];
    auto load_tile = [&](int k0) {
        #pragma unroll
        for (int i = 0; i < 2; ++i) {
            int gr = row0 + am + 32 * i;
            pa[i] = (gr < M) ? *(const float4*)&A[(size_t)gr * K + k0 + ak]
                             : make_float4(0.f, 0.f, 0.f, 0.f);
            pb[i] = *(const float4*)&B[(size_t)(k0 + bk + 16 * i) * N + col0 + bn];
        }
    };
    load_tile(0);
    float acc[4][4] = {};
    for (int k0 = 0; k0 < K; k0 += BK2) {
        __syncthreads();
        #pragma unroll
        for (int i = 0; i < 2; ++i) {
            As[ak + 0][am + 32 * i] = pa[i].x;
            As[ak + 1][am + 32 * i] = pa[i].y;
            As[ak + 2][am + 32 * i] = pa[i].z;
            As[ak + 3][am + 32 * i] = pa[i].w;
            *(float4*)&Bs[bk + 16 * i][bn] = pb[i];
        }
        __syncthreads();
        if (k0 + BK2 < K) load_tile(k0 + BK2);
        #pragma unroll
        for (int kk = 0; kk < BK2; ++kk) {
            float4 a4 = *(const float4*)&As[kk][ty * 4];
            float4 b4 = *(const float4*)&Bs[kk][tx * 4];
            float av[4] = {a4.x, a4.y, a4.z, a4.w};
            float bv[4] = {b4.x, b4.y, b4.z, b4.w};
            #pragma unroll
            for (int i = 0; i < 4; ++i)
                #pragma unroll
                for (int j = 0; j < 4; ++j)
                    acc[i][j] = fmaf(av[i], bv[j], acc[i][j]);
        }
    }
    #pragma unroll
    for (int i = 0; i < 4; ++i) {
        int gr = row0 + ty * 4 + i;
        if (gr < M) {
            float4 v = make_float4(acc[i][0], acc[i][1], acc[i][2], acc[i][3]);
            *(float4*)&C[(size_t)gr * N + col0 + tx * 4] = v;
        }
    }
}

// ---------------- el/er kernels ----------------

// layer-1: el/er per (n,h) row of feat1 [N*8, 64]
__global__ void elr_feat_kernel(const float* __restrict__ feat, const float* __restrict__ al,
                                const float* __restrict__ ar, float* __restrict__ el,
                                float* __restrict__ er, int RH) {
    int idx = blockIdx.x * blockDim.x + threadIdx.x;
    if (idx >= RH) return;
    int h = idx & (HEADS - 1);
    const float* fp = feat + (size_t)idx * HIDDEN;
    float sl = 0.f, sr = 0.f;
    for (int f = 0; f < HIDDEN; ++f) {
        float v = fp[f];
        sl = fmaf(v, al[h * HIDDEN + f], sl);
        sr = fmaf(v, ar[h * HIDDEN + f], sr);
    }
    el[idx] = sl;
    er[idx] = sr;
}

// layers 2/3: one thread per row computes all 8 el + 8 er (row read once).
__global__ void elr_row_kernel(const float* __restrict__ X, const float* __restrict__ alv,
                               const float* __restrict__ arv, float* __restrict__ el,
                               float* __restrict__ er, int R) {
    int r = blockIdx.x * blockDim.x + threadIdx.x;
    if (r >= R) return;
    const float4* x4 = (const float4*)(X + (size_t)r * 64);
    float sl[8] = {}, sr[8] = {};
    for (int kg = 0; kg < 16; ++kg) {
        float4 xv = x4[kg];
        #pragma unroll
        for (int h = 0; h < 8; ++h) {
            float4 a = *(const float4*)&alv[h * 64 + kg * 4];
            float4 b = *(const float4*)&arv[h * 64 + kg * 4];
            sl[h] = fmaf(xv.x, a.x, fmaf(xv.y, a.y, fmaf(xv.z, a.z, fmaf(xv.w, a.w, sl[h]))));
            sr[h] = fmaf(xv.x, b.x, fmaf(xv.y, b.y, fmaf(xv.z, b.z, fmaf(xv.w, b.w, sr[h]))));
        }
    }
    float* elp = el + (size_t)r * 8;
    float* erp = er + (size_t)r * 8;
    #pragma unroll
    for (int h = 0; h < 8; ++h) { elp[h] = sl[h]; erp[h] = sr[h]; }
}

__device__ __forceinline__ float gelu_exact(float v) {
    return 0.5f * v * (1.0f + erff(v * 0.70710678118654752440f));
}

// ---------------- layer-1 aggregation: wave per (node, head-pair), no barriers ----------------
__global__ __launch_bounds__(256) void agg_l1(
    const float* __restrict__ feat, const float* __restrict__ el, const float* __restrict__ er,
    const float* __restrict__ bias, const int* __restrict__ row_ptr,
    const int* __restrict__ csr_src, float* __restrict__ out) {
    int n = blockIdx.x;
    int t = threadIdx.x, wv = t >> 6, lane = t & 63;
    int h0 = 2 * wv;
    int r0 = row_ptr[n], deg = row_ptr[n + 1] - r0;
    float2 erv = *(const float2*)&er[n * 8 + h0];
    float den0 = 0.f, den1 = 0.f, a0 = 0.f, a1 = 0.f;
    for (int i = 0; i < deg; ++i) {
        int s = csr_src[r0 + i];
        float2 elv = *(const float2*)&el[s * 8 + h0];
        float x0 = feat[((size_t)s * 8 + h0) * 64 + lane];
        float x1 = feat[((size_t)s * 8 + h0 + 1) * 64 + lane];
        float e0 = elv.x + erv.x; e0 = e0 > 0.f ? e0 : 0.2f * e0;
        float e1 = elv.y + erv.y; e1 = e1 > 0.f ? e1 : 0.2f * e1;
        float w0 = __expf(e0), w1 = __expf(e1);
        den0 += w0; den1 += w1;
        a0 = fmaf(w0, x0, a0);
        a1 = fmaf(w1, x1, a1);
    }
    float i0 = deg ? 1.f / den0 : 0.f;
    float i1 = deg ? 1.f / den1 : 0.f;
    float v0 = a0 * i0 + bias[h0 * 64 + lane];
    float v1 = a1 * i1 + bias[(h0 + 1) * 64 + lane];
    out[((size_t)n * 8 + h0) * 64 + lane] = gelu_exact(v0);
    out[((size_t)n * 8 + h0 + 1) * 64 + lane] = gelu_exact(v1);
}

// ---------------- layers 2/3: wave-parallel agg (2 p per wave) + fused transform ----------------
// Single-pass softmax without max subtraction (|e| is O(10); fp32 exp safe; ratio identical).
// One barrier per block. W4t layout gives fully coalesced W reads in the transform.
template <int FOUT, bool GELU, int P>
__global__ __launch_bounds__(256) void agg_wave(
    const float* __restrict__ X,     // [N*P, 64]
    const float* __restrict__ el, const float* __restrict__ er,  // [N*P, 8]
    const float* __restrict__ W4t,   // [16][8*FOUT][4]
    const float* __restrict__ bias,  // [8*FOUT]
    const int* __restrict__ row_ptr, const int* __restrict__ csr_src,
    float* __restrict__ out)         // [N*P, 8*FOUT]
{
    constexpr int TOT = 8 * FOUT;
    constexpr int GRPS = P / 8;
    int nb = blockIdx.x;
    int n = nb / GRPS, pg = nb - n * GRPS;
    int p0 = pg * 8;
    int r0 = row_ptr[n], deg = row_ptr[n + 1] - r0;
    int t = threadIdx.x, wv = t >> 6, lane = t & 63;
    __shared__ float acc_s[8][8][68];

    #pragma unroll
    for (int sub = 0; sub < 2; ++sub) {
        int pl = wv * 2 + sub;
        int p = p0 + pl;
        const float* erp = er + ((size_t)n * P + p) * 8;
        float4 er0 = *(const float4*)erp, er1 = *(const float4*)(erp + 4);
        float erv[8] = {er0.x, er0.y, er0.z, er0.w, er1.x, er1.y, er1.z, er1.w};
        float den[8] = {}, agg[8] = {};
        for (int i = 0; i < deg; ++i) {
            int s = csr_src[r0 + i];
            const float* elp = el + ((size_t)s * P + p) * 8;
            float4 e0 = *(const float4*)elp, e1 = *(const float4*)(elp + 4);
            float elv[8] = {e0.x, e0.y, e0.z, e0.w, e1.x, e1.y, e1.z, e1.w};
            float xv = X[((size_t)s * P + p) * 64 + lane];
            #pragma unroll
            for (int h = 0; h < 8; ++h) {
                float e = elv[h] + erv[h];
                e = e > 0.f ? e : 0.2f * e;
                float w = __expf(e);
                den[h] += w;
                agg[h] = fmaf(w, xv, agg[h]);
            }
        }
        #pragma unroll
        for (int h = 0; h < 8; ++h) {
            float inv = deg ? 1.f / den[h] : 0.f;
            acc_s[pl][h][lane] = agg[h] * inv;
        }
    }
    __syncthreads();

    // transform: out[np, idx] = bias[idx] + sum_k acc[p][h][k] * W[k][idx]
    for (int idx = t; idx < TOT; idx += 256) {
        int h = idx / FOUT;
        float val[8];
        #pragma unroll
        for (int pl = 0; pl < 8; ++pl) val[pl] = bias[idx];
        #pragma unroll
        for (int kg = 0; kg < 16; ++kg) {
            float4 w4 = *(const float4*)&W4t[((size_t)kg * TOT + idx) * 4];
            #pragma unroll
            for (int pl = 0; pl < 8; ++pl) {
                float4 a4 = *(const float4*)&acc_s[pl][h][kg * 4];
                val[pl] = fmaf(a4.x, w4.x, fmaf(a4.y, w4.y, fmaf(a4.z, w4.z, fmaf(a4.w, w4.w, val[pl]))));
            }
        }
        #pragma unroll
        for (int pl = 0; pl < 8; ++pl) {
            float v = val[pl];
            if (GELU) v = gelu_exact(v);
            out[((size_t)n * P + p0 + pl) * TOT + idx] = v;
        }
    }
}

// ---------------- launch ----------------

extern "C" void kernel_launch(void* const* d_in, const int* in_sizes, int n_in,
                              void* d_out, int out_size, void* d_ws, size_t ws_size,
                              hipStream_t stream) {
    const float* node = (const float*)d_in[0];
    const int* src = (const int*)d_in[1];
    const int* dst = (const int*)d_in[2];
    const float* W1 = (const float*)d_in[3];
    const float* al1 = (const float*)d_in[4];
    const float* ar1 = (const float*)d_in[5];
    const float* b1 = (const float*)d_in[6];
    const float* W2 = (const float*)d_in[7];
    const float* al2 = (const float*)d_in[8];
    const float* ar2 = (const float*)d_in[9];
    const float* b2 = (const float*)d_in[10];
    const float* W3 = (const float*)d_in[11];
    const float* al3 = (const float*)d_in[12];
    const float* ar3 = (const float*)d_in[13];
    const float* b3 = (const float*)d_in[14];
    float* out = (float*)d_out;

    char* ws = (char*)d_ws;
    size_t off = 0;
    auto alloc = [&](size_t nb) -> char* {
        char* q = ws + off;
        off += (nb + 255) & ~(size_t)255;
        return q;
    };
    int* counts   = (int*)alloc((N_NODES + 1) * sizeof(int));
    int* row_ptr  = (int*)alloc((N_NODES + 1) * sizeof(int));
    int* csr_src  = (int*)alloc(N_EDGES * sizeof(int));
    float* feat1  = (float*)alloc((size_t)N_NODES * 8 * 64 * 4);
    float* el1    = (float*)alloc((size_t)N_NODES * 8 * 4);
    float* er1    = (float*)alloc((size_t)N_NODES * 8 * 4);
    float* h1     = (float*)alloc((size_t)N_NODES * 8 * 64 * 4);
    float* aleff2 = (float*)alloc(8 * 64 * 4);
    float* areff2 = (float*)alloc(8 * 64 * 4);
    float* el2    = (float*)alloc((size_t)N_NODES * 8 * 8 * 4);
    float* er2    = (float*)alloc((size_t)N_NODES * 8 * 8 * 4);
    float* h2     = (float*)alloc((size_t)N_NODES * 64 * 64 * 4);
    float* aleff3 = (float*)alloc(8 * 64 * 4);
    float* areff3 = (float*)alloc(8 * 64 * 4);
    float* el3    = (float*)alloc((size_t)N_NODES * 64 * 8 * 4);
    float* er3    = (float*)alloc((size_t)N_NODES * 64 * 8 * 4);
    float* W4t2   = (float*)alloc((size_t)16 * 512 * 4 * 4);
    float* W4t3   = (float*)alloc((size_t)16 * 256 * 4 * 4);

    // prep: zero counts + att-eff vectors + W reshuffles (one kernel)
    const int PREP_T = 1536 + 1024 + 1024 + 16 * 512 * 4 + 16 * 256 * 4;
    prep_kernel<<<(PREP_T + 255) / 256, 256, 0, stream>>>(
        W2, al2, ar2, W3, al3, ar3, aleff2, areff2, aleff3, areff3, W4t2, W4t3, counts);

    hist_kernel<<<(N_EDGES + 255) / 256, 256, 0, stream>>>(dst, counts);
    scan_kernel<<<1, 256, 0, stream>>>(counts, row_ptr);
    build_csr_kernel<<<(N_NODES * 64 + 255) / 256, 256, 0, stream>>>(dst, src, row_ptr, csr_src);

    // ---- layer 1 ----
    dim3 g1(512 / BN, (N_NODES + BM - 1) / BM);
    gemm_f32<<<g1, 256, 0, stream>>>(node, W1, feat1, N_NODES, 512, IN_FEAT);
    elr_feat_kernel<<<(N_NODES * 8 + 255) / 256, 256, 0, stream>>>(feat1, al1, ar1, el1, er1, N_NODES * 8);
    agg_l1<<<N_NODES, 256, 0, stream>>>(feat1, el1, er1, b1, row_ptr, csr_src, h1);

    // ---- layer 2 ----
    elr_row_kernel<<<(N_NODES * 8 + 255) / 256, 256, 0, stream>>>(h1, aleff2, areff2, el2, er2, N_NODES * 8);
    agg_wave<64, true, 8><<<N_NODES, 256, 0, stream>>>(h1, el2, er2, W4t2, b2, row_ptr, csr_src, h2);

    // ---- layer 3 ----
    elr_row_kernel<<<(N_NODES * 64 + 255) / 256, 256, 0, stream>>>(h2, aleff3, areff3, el3, er3, N_NODES * 64);
    agg_wave<32, false, 64><<<N_NODES * 8, 256, 0, stream>>>(h2, el3, er3, W4t3, b3, row_ptr, csr_src, out);
}

// Round 4
// 304.423 us; speedup vs baseline: 3.4738x; 1.2322x over previous
//
#include <hip/hip_runtime.h>
#include <math.h>

#define N_NODES 1500
#define N_EDGES 12000
#define IN_FEAT 512
#define HIDDEN 64
#define OUT_FEAT 32
#define HEADS 8

// ---------------- fused prep: zero counts + att-eff vectors + W reshuffle ----------------
// W4t layout: W4t[(kg*TOT + c)*4 + j] = W[(kg*4+j)*TOT + c]  (kg<16, j<4, c<TOT)

__global__ void prep_kernel(const float* __restrict__ W2, const float* __restrict__ al2,
                            const float* __restrict__ ar2,
                            const float* __restrict__ W3, const float* __restrict__ al3,
                            const float* __restrict__ ar3,
                            float* __restrict__ aleff2, float* __restrict__ areff2,
                            float* __restrict__ aleff3, float* __restrict__ areff3,
                            float* __restrict__ W4t2, float* __restrict__ W4t3,
                            int* __restrict__ counts) {
    int i = blockIdx.x * blockDim.x + threadIdx.x;
    if (i < 1536) {
        if (i < N_NODES + 1) counts[i] = 0;
        return;
    }
    i -= 1536;
    if (i < 1024) {  // aleff2 / areff2: [h][64]
        int lr = i >> 9; i &= 511;
        int h = i >> 6, k = i & 63;
        const float* a = lr ? ar2 : al2;
        float s = 0.f;
        for (int f = 0; f < 64; ++f)
            s = fmaf(W2[(size_t)k * 512 + h * 64 + f], a[h * 64 + f], s);
        (lr ? areff2 : aleff2)[h * 64 + k] = s;
        return;
    }
    i -= 1024;
    if (i < 1024) {  // aleff3 / areff3
        int lr = i >> 9; i &= 511;
        int h = i >> 6, k = i & 63;
        const float* a = lr ? ar3 : al3;
        float s = 0.f;
        for (int f = 0; f < 32; ++f)
            s = fmaf(W3[(size_t)k * 256 + h * 32 + f], a[h * 32 + f], s);
        (lr ? areff3 : aleff3)[h * 64 + k] = s;
        return;
    }
    i -= 1024;
    if (i < 16 * 512 * 4) {  // W4t2 (TOT=512)
        int kg = i >> 11, rem = i & 2047;
        int c = rem >> 2, j = rem & 3;
        W4t2[i] = W2[(size_t)(kg * 4 + j) * 512 + c];
        return;
    }
    i -= 16 * 512 * 4;
    if (i < 16 * 256 * 4) {  // W4t3 (TOT=256)
        int kg = i >> 10, rem = i & 1023;
        int c = rem >> 2, j = rem & 3;
        W4t3[i] = W3[(size_t)(kg * 4 + j) * 256 + c];
    }
}

__global__ void hist_kernel(const int* __restrict__ dst, int* __restrict__ counts) {
    int e = blockIdx.x * blockDim.x + threadIdx.x;
    if (e < N_EDGES) atomicAdd(&counts[dst[e]], 1);
}

__global__ void scan_kernel(const int* __restrict__ counts, int* __restrict__ row_ptr) {
    __shared__ int part[256];
    int t = threadIdx.x;
    const int CH = (N_NODES + 255) / 256;
    int base = t * CH;
    int loc[8];
    int s = 0;
    for (int i = 0; i < CH; ++i) {
        int idx = base + i;
        int v = (idx < N_NODES) ? counts[idx] : 0;
        loc[i] = s;
        s += v;
    }
    part[t] = s;
    __syncthreads();
    if (t == 0) {
        int a = 0;
        for (int i = 0; i < 256; ++i) { int v = part[i]; part[i] = a; a += v; }
        row_ptr[N_NODES] = a;
    }
    __syncthreads();
    int p0 = part[t];
    for (int i = 0; i < CH; ++i) {
        int idx = base + i;
        if (idx < N_NODES) row_ptr[idx] = p0 + loc[i];
    }
}

// wave-per-node stable CSR build; stores SRC NODE ID directly (csr_src).
__global__ void build_csr_kernel(const int* __restrict__ dst, const int* __restrict__ src,
                                 const int* __restrict__ row_ptr, int* __restrict__ csr_src) {
    int wid = (blockIdx.x * blockDim.x + threadIdx.x) >> 6;
    int lane = threadIdx.x & 63;
    if (wid >= N_NODES) return;
    int pos = row_ptr[wid];
    for (int base = 0; base < N_EDGES; base += 64) {
        int e = base + lane;
        bool hit = (e < N_EDGES) && (dst[e] == wid);
        unsigned long long m = __ballot(hit);
        if (hit) {
            int r = __popcll(m & ((1ull << lane) - 1ull));
            csr_src[pos + r] = src[e];
        }
        pos += __popcll(m);
    }
}

// ---------------- f32 tiled GEMM (layer 1): BK=32, register prefetch ----------------

#define BM 64
#define BN 64
#define BK2 32

__global__ __launch_bounds__(256) void gemm_f32(const float* __restrict__ A,
                                                const float* __restrict__ B,
                                                float* __restrict__ C,
                                                int M, int N, int K) {
    __shared__ float As[BK2][BM + 4];
    __shared__ float Bs[BK2][BN + 4];
    int t = threadIdx.x;
    int col0 = blockIdx.x * BN, row0 = blockIdx.y * BM;
    int tx = t & 15, ty = t >> 4;
    int am = t >> 3, ak = (t & 7) * 4;
    int bk = t >> 4, bn = (t & 15) * 4;
    float4 pa[2], pb[2];
    auto load_tile = [&](int k0) {
        #pragma unroll
        for (int i = 0; i < 2; ++i) {
            int gr = row0 + am + 32 * i;
            pa[i] = (gr < M) ? *(const float4*)&A[(size_t)gr * K + k0 + ak]
                             : make_float4(0.f, 0.f, 0.f, 0.f);
            pb[i] = *(const float4*)&B[(size_t)(k0 + bk + 16 * i) * N + col0 + bn];
        }
    };
    load_tile(0);
    float acc[4][4] = {};
    for (int k0 = 0; k0 < K; k0 += BK2) {
        __syncthreads();
        #pragma unroll
        for (int i = 0; i < 2; ++i) {
            As[ak + 0][am + 32 * i] = pa[i].x;
            As[ak + 1][am + 32 * i] = pa[i].y;
            As[ak + 2][am + 32 * i] = pa[i].z;
            As[ak + 3][am + 32 * i] = pa[i].w;
            *(float4*)&Bs[bk + 16 * i][bn] = pb[i];
        }
        __syncthreads();
        if (k0 + BK2 < K) load_tile(k0 + BK2);
        #pragma unroll
        for (int kk = 0; kk < BK2; ++kk) {
            float4 a4 = *(const float4*)&As[kk][ty * 4];
            float4 b4 = *(const float4*)&Bs[kk][tx * 4];
            float av[4] = {a4.x, a4.y, a4.z, a4.w};
            float bv[4] = {b4.x, b4.y, b4.z, b4.w};
            #pragma unroll
            for (int i = 0; i < 4; ++i)
                #pragma unroll
                for (int j = 0; j < 4; ++j)
                    acc[i][j] = fmaf(av[i], bv[j], acc[i][j]);
        }
    }
    #pragma unroll
    for (int i = 0; i < 4; ++i) {
        int gr = row0 + ty * 4 + i;
        if (gr < M) {
            float4 v = make_float4(acc[i][0], acc[i][1], acc[i][2], acc[i][3]);
            *(float4*)&C[(size_t)gr * N + col0 + tx * 4] = v;
        }
    }
}

// ---------------- el/er kernels ----------------

__global__ void elr_feat_kernel(const float* __restrict__ feat, const float* __restrict__ al,
                                const float* __restrict__ ar, float* __restrict__ el,
                                float* __restrict__ er, int RH) {
    int idx = blockIdx.x * blockDim.x + threadIdx.x;
    if (idx >= RH) return;
    int h = idx & (HEADS - 1);
    const float* fp = feat + (size_t)idx * HIDDEN;
    float sl = 0.f, sr = 0.f;
    for (int f = 0; f < HIDDEN; ++f) {
        float v = fp[f];
        sl = fmaf(v, al[h * HIDDEN + f], sl);
        sr = fmaf(v, ar[h * HIDDEN + f], sr);
    }
    el[idx] = sl;
    er[idx] = sr;
}

__global__ void elr_row_kernel(const float* __restrict__ X, const float* __restrict__ alv,
                               const float* __restrict__ arv, float* __restrict__ el,
                               float* __restrict__ er, int R) {
    int r = blockIdx.x * blockDim.x + threadIdx.x;
    if (r >= R) return;
    const float4* x4 = (const float4*)(X + (size_t)r * 64);
    float sl[8] = {}, sr[8] = {};
    for (int kg = 0; kg < 16; ++kg) {
        float4 xv = x4[kg];
        #pragma unroll
        for (int h = 0; h < 8; ++h) {
            float4 a = *(const float4*)&alv[h * 64 + kg * 4];
            float4 b = *(const float4*)&arv[h * 64 + kg * 4];
            sl[h] = fmaf(xv.x, a.x, fmaf(xv.y, a.y, fmaf(xv.z, a.z, fmaf(xv.w, a.w, sl[h]))));
            sr[h] = fmaf(xv.x, b.x, fmaf(xv.y, b.y, fmaf(xv.z, b.z, fmaf(xv.w, b.w, sr[h]))));
        }
    }
    float* elp = el + (size_t)r * 8;
    float* erp = er + (size_t)r * 8;
    #pragma unroll
    for (int h = 0; h < 8; ++h) { elp[h] = sl[h]; erp[h] = sr[h]; }
}

__device__ __forceinline__ float gelu_exact(float v) {
    return 0.5f * v * (1.0f + erff(v * 0.70710678118654752440f));
}

// ---------------- layer-1 aggregation: wave per (node, head-pair) ----------------
__global__ __launch_bounds__(256) void agg_l1(
    const float* __restrict__ feat, const float* __restrict__ el, const float* __restrict__ er,
    const float* __restrict__ bias, const int* __restrict__ row_ptr,
    const int* __restrict__ csr_src, float* __restrict__ out) {
    int n = blockIdx.x;
    int t = threadIdx.x, wv = t >> 6, lane = t & 63;
    int h0 = 2 * wv;
    int r0 = row_ptr[n], deg = row_ptr[n + 1] - r0;
    float2 erv = *(const float2*)&er[n * 8 + h0];
    float den0 = 0.f, den1 = 0.f, a0 = 0.f, a1 = 0.f;
    for (int i = 0; i < deg; ++i) {
        int s = csr_src[r0 + i];
        float2 elv = *(const float2*)&el[s * 8 + h0];
        float x0 = feat[((size_t)s * 8 + h0) * 64 + lane];
        float x1 = feat[((size_t)s * 8 + h0 + 1) * 64 + lane];
        float e0 = elv.x + erv.x; e0 = e0 > 0.f ? e0 : 0.2f * e0;
        float e1 = elv.y + erv.y; e1 = e1 > 0.f ? e1 : 0.2f * e1;
        float w0 = __expf(e0), w1 = __expf(e1);
        den0 += w0; den1 += w1;
        a0 = fmaf(w0, x0, a0);
        a1 = fmaf(w1, x1, a1);
    }
    float i0 = deg ? 1.f / den0 : 0.f;
    float i1 = deg ? 1.f / den1 : 0.f;
    float v0 = a0 * i0 + bias[h0 * 64 + lane];
    float v1 = a1 * i1 + bias[(h0 + 1) * 64 + lane];
    out[((size_t)n * 8 + h0) * 64 + lane] = gelu_exact(v0);
    out[((size_t)n * 8 + h0 + 1) * 64 + lane] = gelu_exact(v1);
}

// ---------------- layers 2/3: LDS-staged weights + register-blocked transform ----------------
// Block = (node, p-group of 8). Phases:
//   W: weights w[i][pl][h] computed once into LDS (+den in 64 stat threads)
//   A: wave wv aggregates pl=2wv,2wv+1; per edge: 2 broadcast b128 w-reads + 1 X load + 8 FMA
//   T: thread (kq,h,fq) holds W regs for 4 f; sweeps 8 pl per acc b128 -> 16 FMA/b128
//   R: float4 reduce of KSPLIT partials + bias + gelu + store
template <int FOUT, bool GELU, int P>
__global__ __launch_bounds__(256) void agg_fused3(
    const float* __restrict__ X,     // [N*P, 64]
    const float* __restrict__ el, const float* __restrict__ er,  // [N*P, 8]
    const float* __restrict__ W4t,   // [16][8*FOUT][4]
    const float* __restrict__ bias,  // [8*FOUT]
    const int* __restrict__ row_ptr, const int* __restrict__ csr_src,
    float* __restrict__ out)         // [N*P, 8*FOUT]
{
    constexpr int TOT = 8 * FOUT;
    constexpr int KSPLIT = 128 / FOUT;       // 4 (L3), 2 (L2)
    constexpr int KGPT = 16 / KSPLIT;        // kg per thread
    constexpr int FQ = FOUT / 4;
    constexpr int TPK = 8 * FQ;              // threads per kq slice
    constexpr int PTS = FOUT + 4;            // padded partial stride
    constexpr int WPSZ = (KSPLIT * 64 * PTS > 64 * 64) ? KSPLIT * 64 * PTS : 64 * 64;
    constexpr int GRPS = P / 8;
    constexpr int CHUNK = 64;

    int nb = blockIdx.x;
    int n = nb / GRPS, pg = nb - n * GRPS;
    int p0 = pg * 8;
    int r0 = row_ptr[n], deg = row_ptr[n + 1] - r0;
    int t = threadIdx.x, wv = t >> 6, lane = t & 63;

    __shared__ int src_s[CHUNK];
    __shared__ float inv_s[64];
    __shared__ float acc_s[8][8][68];
    __shared__ float wp_lds[WPSZ];   // union: w[i][pl][h] (phase W/A) | partials (phase T/R)

    float agg0[8], agg1[8];
    #pragma unroll
    for (int h = 0; h < 8; ++h) { agg0[h] = 0.f; agg1[h] = 0.f; }
    float den = 0.f;  // stat threads t<64: (pl,h) = (t>>3, t&7)

    int elbase_n = (n * P + p0) * 8;

    for (int c0 = 0; c0 < deg; c0 += CHUNK) {
        int cnt = min(deg - c0, CHUNK);
        __syncthreads();
        if (t < cnt) src_s[t] = csr_src[r0 + c0 + t];
        for (int j = t; j < cnt * 64; j += 256) {
            int i = j >> 6, plh = j & 63;
            int s = csr_src[r0 + c0 + i];
            float e = el[(s * P + p0) * 8 + plh] + er[elbase_n + plh];
            e = e > 0.f ? e : 0.2f * e;
            wp_lds[i * 64 + plh] = __expf(e);
        }
        __syncthreads();
        if (t < 64) {
            for (int i = 0; i < cnt; ++i) den += wp_lds[i * 64 + t];
        }
        int pA = p0 + wv * 2;
        for (int i = 0; i < cnt; ++i) {
            int s = src_s[i];
            const float* wp = &wp_lds[i * 64 + wv * 16];
            float4 w0 = *(const float4*)wp;
            float4 w1 = *(const float4*)(wp + 4);
            float4 w2 = *(const float4*)(wp + 8);
            float4 w3 = *(const float4*)(wp + 12);
            int xb = (s * P + pA) * 64 + lane;
            float xv0 = X[xb];
            float xv1 = X[xb + 64];
            agg0[0] = fmaf(w0.x, xv0, agg0[0]);
            agg0[1] = fmaf(w0.y, xv0, agg0[1]);
            agg0[2] = fmaf(w0.z, xv0, agg0[2]);
            agg0[3] = fmaf(w0.w, xv0, agg0[3]);
            agg0[4] = fmaf(w1.x, xv0, agg0[4]);
            agg0[5] = fmaf(w1.y, xv0, agg0[5]);
            agg0[6] = fmaf(w1.z, xv0, agg0[6]);
            agg0[7] = fmaf(w1.w, xv0, agg0[7]);
            agg1[0] = fmaf(w2.x, xv1, agg1[0]);
            agg1[1] = fmaf(w2.y, xv1, agg1[1]);
            agg1[2] = fmaf(w2.z, xv1, agg1[2]);
            agg1[3] = fmaf(w2.w, xv1, agg1[3]);
            agg1[4] = fmaf(w3.x, xv1, agg1[4]);
            agg1[5] = fmaf(w3.y, xv1, agg1[5]);
            agg1[6] = fmaf(w3.z, xv1, agg1[6]);
            agg1[7] = fmaf(w3.w, xv1, agg1[7]);
        }
    }
    if (t < 64) inv_s[t] = deg ? 1.f / den : 0.f;
    __syncthreads();
    {
        int pl0 = wv * 2;
        #pragma unroll
        for (int h = 0; h < 8; ++h) {
            acc_s[pl0][h][lane] = agg0[h] * inv_s[pl0 * 8 + h];
            acc_s[pl0 + 1][h][lane] = agg1[h] * inv_s[pl0 * 8 + 8 + h];
        }
    }
    __syncthreads();

    // phase T: partial transforms into wp_lds (w_lds dead now)
    {
        int kq = t / TPK, rem = t % TPK;
        int h = rem / FQ, fq = rem % FQ;
        int f0 = fq * 4;
        float part[8][4];
        #pragma unroll
        for (int pl = 0; pl < 8; ++pl)
            #pragma unroll
            for (int q = 0; q < 4; ++q) part[pl][q] = 0.f;
        #pragma unroll
        for (int kk = 0; kk < KGPT; ++kk) {
            int kg = kq * KGPT + kk;
            float4 wr0 = *(const float4*)&W4t[(kg * TOT + h * FOUT + f0 + 0) * 4];
            float4 wr1 = *(const float4*)&W4t[(kg * TOT + h * FOUT + f0 + 1) * 4];
            float4 wr2 = *(const float4*)&W4t[(kg * TOT + h * FOUT + f0 + 2) * 4];
            float4 wr3 = *(const float4*)&W4t[(kg * TOT + h * FOUT + f0 + 3) * 4];
            #pragma unroll
            for (int pl = 0; pl < 8; ++pl) {
                float4 a4 = *(const float4*)&acc_s[pl][h][kg * 4];
                part[pl][0] = fmaf(a4.x, wr0.x, fmaf(a4.y, wr0.y, fmaf(a4.z, wr0.z, fmaf(a4.w, wr0.w, part[pl][0]))));
                part[pl][1] = fmaf(a4.x, wr1.x, fmaf(a4.y, wr1.y, fmaf(a4.z, wr1.z, fmaf(a4.w, wr1.w, part[pl][1]))));
                part[pl][2] = fmaf(a4.x, wr2.x, fmaf(a4.y, wr2.y, fmaf(a4.z, wr2.z, fmaf(a4.w, wr2.w, part[pl][2]))));
                part[pl][3] = fmaf(a4.x, wr3.x, fmaf(a4.y, wr3.y, fmaf(a4.z, wr3.z, fmaf(a4.w, wr3.w, part[pl][3]))));
            }
        }
        #pragma unroll
        for (int pl = 0; pl < 8; ++pl) {
            float4 v = make_float4(part[pl][0], part[pl][1], part[pl][2], part[pl][3]);
            *(float4*)&wp_lds[((kq * 8 + pl) * 8 + h) * PTS + f0] = v;
        }
    }
    __syncthreads();

    // phase R: reduce KSPLIT partials, bias, (gelu), store
    {
        constexpr int NQ = 2 * TOT;          // number of float4 outputs per block
        for (int q = t; q < NQ; q += 256) {
            int pl = q / (TOT / 4);
            int rem = q - pl * (TOT / 4);
            int h = rem / FQ, fq = rem - h * FQ;
            int f0 = fq * 4;
            float4 acc4 = *(const float4*)&wp_lds[((0 * 8 + pl) * 8 + h) * PTS + f0];
            #pragma unroll
            for (int kq = 1; kq < KSPLIT; ++kq) {
                float4 pv = *(const float4*)&wp_lds[((kq * 8 + pl) * 8 + h) * PTS + f0];
                acc4.x += pv.x; acc4.y += pv.y; acc4.z += pv.z; acc4.w += pv.w;
            }
            float4 b4 = *(const float4*)&bias[h * FOUT + f0];
            acc4.x += b4.x; acc4.y += b4.y; acc4.z += b4.z; acc4.w += b4.w;
            if (GELU) {
                acc4.x = gelu_exact(acc4.x); acc4.y = gelu_exact(acc4.y);
                acc4.z = gelu_exact(acc4.z); acc4.w = gelu_exact(acc4.w);
            }
            *(float4*)&out[(size_t)(n * P + p0 + pl) * TOT + h * FOUT + f0] = acc4;
        }
    }
}

// ---------------- launch ----------------

extern "C" void kernel_launch(void* const* d_in, const int* in_sizes, int n_in,
                              void* d_out, int out_size, void* d_ws, size_t ws_size,
                              hipStream_t stream) {
    const float* node = (const float*)d_in[0];
    const int* src = (const int*)d_in[1];
    const int* dst = (const int*)d_in[2];
    const float* W1 = (const float*)d_in[3];
    const float* al1 = (const float*)d_in[4];
    const float* ar1 = (const float*)d_in[5];
    const float* b1 = (const float*)d_in[6];
    const float* W2 = (const float*)d_in[7];
    const float* al2 = (const float*)d_in[8];
    const float* ar2 = (const float*)d_in[9];
    const float* b2 = (const float*)d_in[10];
    const float* W3 = (const float*)d_in[11];
    const float* al3 = (const float*)d_in[12];
    const float* ar3 = (const float*)d_in[13];
    const float* b3 = (const float*)d_in[14];
    float* out = (float*)d_out;

    char* ws = (char*)d_ws;
    size_t off = 0;
    auto alloc = [&](size_t nb) -> char* {
        char* q = ws + off;
        off += (nb + 255) & ~(size_t)255;
        return q;
    };
    int* counts   = (int*)alloc((N_NODES + 1) * sizeof(int));
    int* row_ptr  = (int*)alloc((N_NODES + 1) * sizeof(int));
    int* csr_src  = (int*)alloc(N_EDGES * sizeof(int));
    float* feat1  = (float*)alloc((size_t)N_NODES * 8 * 64 * 4);
    float* el1    = (float*)alloc((size_t)N_NODES * 8 * 4);
    float* er1    = (float*)alloc((size_t)N_NODES * 8 * 4);
    float* h1     = (float*)alloc((size_t)N_NODES * 8 * 64 * 4);
    float* aleff2 = (float*)alloc(8 * 64 * 4);
    float* areff2 = (float*)alloc(8 * 64 * 4);
    float* el2    = (float*)alloc((size_t)N_NODES * 8 * 8 * 4);
    float* er2    = (float*)alloc((size_t)N_NODES * 8 * 8 * 4);
    float* h2     = (float*)alloc((size_t)N_NODES * 64 * 64 * 4);
    float* aleff3 = (float*)alloc(8 * 64 * 4);
    float* areff3 = (float*)alloc(8 * 64 * 4);
    float* el3    = (float*)alloc((size_t)N_NODES * 64 * 8 * 4);
    float* er3    = (float*)alloc((size_t)N_NODES * 64 * 8 * 4);
    float* W4t2   = (float*)alloc((size_t)16 * 512 * 4 * 4);
    float* W4t3   = (float*)alloc((size_t)16 * 256 * 4 * 4);

    const int PREP_T = 1536 + 1024 + 1024 + 16 * 512 * 4 + 16 * 256 * 4;
    prep_kernel<<<(PREP_T + 255) / 256, 256, 0, stream>>>(
        W2, al2, ar2, W3, al3, ar3, aleff2, areff2, aleff3, areff3, W4t2, W4t3, counts);

    hist_kernel<<<(N_EDGES + 255) / 256, 256, 0, stream>>>(dst, counts);
    scan_kernel<<<1, 256, 0, stream>>>(counts, row_ptr);
    build_csr_kernel<<<(N_NODES * 64 + 255) / 256, 256, 0, stream>>>(dst, src, row_ptr, csr_src);

    // ---- layer 1 ----
    dim3 g1(512 / BN, (N_NODES + BM - 1) / BM);
    gemm_f32<<<g1, 256, 0, stream>>>(node, W1, feat1, N_NODES, 512, IN_FEAT);
    elr_feat_kernel<<<(N_NODES * 8 + 255) / 256, 256, 0, stream>>>(feat1, al1, ar1, el1, er1, N_NODES * 8);
    agg_l1<<<N_NODES, 256, 0, stream>>>(feat1, el1, er1, b1, row_ptr, csr_src, h1);

    // ---- layer 2 ----
    elr_row_kernel<<<(N_NODES * 8 + 255) / 256, 256, 0, stream>>>(h1, aleff2, areff2, el2, er2, N_NODES * 8);
    agg_fused3<64, true, 8><<<N_NODES, 256, 0, stream>>>(h1, el2, er2, W4t2, b2, row_ptr, csr_src, h2);

    // ---- layer 3 ----
    elr_row_kernel<<<(N_NODES * 64 + 255) / 256, 256, 0, stream>>>(h2, aleff3, areff3, el3, er3, N_NODES * 64);
    agg_fused3<32, false, 64><<<N_NODES * 8, 256, 0, stream>>>(h2, el3, er3, W4t3, b3, row_ptr, csr_src, out);
}

// Round 5
// 252.878 us; speedup vs baseline: 4.1819x; 1.2038x over previous
//
#include <hip/hip_runtime.h>
#include <math.h>

#define N_NODES 1500
#define N_EDGES 12000
#define IN_FEAT 512
#define HIDDEN 64
#define OUT_FEAT 32
#define HEADS 8

// ---------------- fused prep: zero counts + att-eff vectors + W reshuffle ----------------
// W4t layout: W4t[(kg*TOT + c)*4 + j] = W[(kg*4+j)*TOT + c]  (kg<16, j<4, c<TOT)

__global__ void prep_kernel(const float* __restrict__ W2, const float* __restrict__ al2,
                            const float* __restrict__ ar2,
                            const float* __restrict__ W3, const float* __restrict__ al3,
                            const float* __restrict__ ar3,
                            float* __restrict__ aleff2, float* __restrict__ areff2,
                            float* __restrict__ aleff3, float* __restrict__ areff3,
                            float* __restrict__ W4t2, float* __restrict__ W4t3,
                            int* __restrict__ counts) {
    int i = blockIdx.x * blockDim.x + threadIdx.x;
    if (i < 1536) {
        if (i < N_NODES + 1) counts[i] = 0;
        return;
    }
    i -= 1536;
    if (i < 1024) {  // aleff2 / areff2: [h][64]
        int lr = i >> 9; i &= 511;
        int h = i >> 6, k = i & 63;
        const float* a = lr ? ar2 : al2;
        float s = 0.f;
        for (int f = 0; f < 64; ++f)
            s = fmaf(W2[(size_t)k * 512 + h * 64 + f], a[h * 64 + f], s);
        (lr ? areff2 : aleff2)[h * 64 + k] = s;
        return;
    }
    i -= 1024;
    if (i < 1024) {  // aleff3 / areff3
        int lr = i >> 9; i &= 511;
        int h = i >> 6, k = i & 63;
        const float* a = lr ? ar3 : al3;
        float s = 0.f;
        for (int f = 0; f < 32; ++f)
            s = fmaf(W3[(size_t)k * 256 + h * 32 + f], a[h * 32 + f], s);
        (lr ? areff3 : aleff3)[h * 64 + k] = s;
        return;
    }
    i -= 1024;
    if (i < 16 * 512 * 4) {  // W4t2 (TOT=512)
        int kg = i >> 11, rem = i & 2047;
        int c = rem >> 2, j = rem & 3;
        W4t2[i] = W2[(size_t)(kg * 4 + j) * 512 + c];
        return;
    }
    i -= 16 * 512 * 4;
    if (i < 16 * 256 * 4) {  // W4t3 (TOT=256)
        int kg = i >> 10, rem = i & 1023;
        int c = rem >> 2, j = rem & 3;
        W4t3[i] = W3[(size_t)(kg * 4 + j) * 256 + c];
    }
}

__global__ void hist_kernel(const int* __restrict__ dst, int* __restrict__ counts) {
    int e = blockIdx.x * blockDim.x + threadIdx.x;
    if (e < N_EDGES) atomicAdd(&counts[dst[e]], 1);
}

__global__ void scan_kernel(const int* __restrict__ counts, int* __restrict__ row_ptr) {
    __shared__ int part[256];
    int t = threadIdx.x;
    const int CH = (N_NODES + 255) / 256;
    int base = t * CH;
    int loc[8];
    int s = 0;
    for (int i = 0; i < CH; ++i) {
        int idx = base + i;
        int v = (idx < N_NODES) ? counts[idx] : 0;
        loc[i] = s;
        s += v;
    }
    part[t] = s;
    __syncthreads();
    if (t == 0) {
        int a = 0;
        for (int i = 0; i < 256; ++i) { int v = part[i]; part[i] = a; a += v; }
        row_ptr[N_NODES] = a;
    }
    __syncthreads();
    int p0 = part[t];
    for (int i = 0; i < CH; ++i) {
        int idx = base + i;
        if (idx < N_NODES) row_ptr[idx] = p0 + loc[i];
    }
}

// wave-per-node stable CSR build; stores SRC NODE ID directly (csr_src).
__global__ void build_csr_kernel(const int* __restrict__ dst, const int* __restrict__ src,
                                 const int* __restrict__ row_ptr, int* __restrict__ csr_src) {
    int wid = (blockIdx.x * blockDim.x + threadIdx.x) >> 6;
    int lane = threadIdx.x & 63;
    if (wid >= N_NODES) return;
    int pos = row_ptr[wid];
    for (int base = 0; base < N_EDGES; base += 64) {
        int e = base + lane;
        bool hit = (e < N_EDGES) && (dst[e] == wid);
        unsigned long long m = __ballot(hit);
        if (hit) {
            int r = __popcll(m & ((1ull << lane) - 1ull));
            csr_src[pos + r] = src[e];
        }
        pos += __popcll(m);
    }
}

// ---------------- f32 tiled GEMM (layer 1): BK=32, register prefetch ----------------

#define BM 64
#define BN 64
#define BK2 32

__global__ __launch_bounds__(256) void gemm_f32(const float* __restrict__ A,
                                                const float* __restrict__ B,
                                                float* __restrict__ C,
                                                int M, int N, int K) {
    __shared__ float As[BK2][BM + 4];
    __shared__ float Bs[BK2][BN + 4];
    int t = threadIdx.x;
    int col0 = blockIdx.x * BN, row0 = blockIdx.y * BM;
    int tx = t & 15, ty = t >> 4;
    int am = t >> 3, ak = (t & 7) * 4;
    int bk = t >> 4, bn = (t & 15) * 4;
    float4 pa[2], pb[2];
    auto load_tile = [&](int k0) {
        #pragma unroll
        for (int i = 0; i < 2; ++i) {
            int gr = row0 + am + 32 * i;
            pa[i] = (gr < M) ? *(const float4*)&A[(size_t)gr * K + k0 + ak]
                             : make_float4(0.f, 0.f, 0.f, 0.f);
            pb[i] = *(const float4*)&B[(size_t)(k0 + bk + 16 * i) * N + col0 + bn];
        }
    };
    load_tile(0);
    float acc[4][4] = {};
    for (int k0 = 0; k0 < K; k0 += BK2) {
        __syncthreads();
        #pragma unroll
        for (int i = 0; i < 2; ++i) {
            As[ak + 0][am + 32 * i] = pa[i].x;
            As[ak + 1][am + 32 * i] = pa[i].y;
            As[ak + 2][am + 32 * i] = pa[i].z;
            As[ak + 3][am + 32 * i] = pa[i].w;
            *(float4*)&Bs[bk + 16 * i][bn] = pb[i];
        }
        __syncthreads();
        if (k0 + BK2 < K) load_tile(k0 + BK2);
        #pragma unroll
        for (int kk = 0; kk < BK2; ++kk) {
            float4 a4 = *(const float4*)&As[kk][ty * 4];
            float4 b4 = *(const float4*)&Bs[kk][tx * 4];
            float av[4] = {a4.x, a4.y, a4.z, a4.w};
            float bv[4] = {b4.x, b4.y, b4.z, b4.w};
            #pragma unroll
            for (int i = 0; i < 4; ++i)
                #pragma unroll
                for (int j = 0; j < 4; ++j)
                    acc[i][j] = fmaf(av[i], bv[j], acc[i][j]);
        }
    }
    #pragma unroll
    for (int i = 0; i < 4; ++i) {
        int gr = row0 + ty * 4 + i;
        if (gr < M) {
            float4 v = make_float4(acc[i][0], acc[i][1], acc[i][2], acc[i][3]);
            *(float4*)&C[(size_t)gr * N + col0 + tx * 4] = v;
        }
    }
}

// ---------------- el/er kernels ----------------

__global__ void elr_feat_kernel(const float* __restrict__ feat, const float* __restrict__ al,
                                const float* __restrict__ ar, float* __restrict__ el,
                                float* __restrict__ er, int RH) {
    int idx = blockIdx.x * blockDim.x + threadIdx.x;
    if (idx >= RH) return;
    int h = idx & (HEADS - 1);
    const float* fp = feat + (size_t)idx * HIDDEN;
    float sl = 0.f, sr = 0.f;
    for (int f = 0; f < HIDDEN; ++f) {
        float v = fp[f];
        sl = fmaf(v, al[h * HIDDEN + f], sl);
        sr = fmaf(v, ar[h * HIDDEN + f], sr);
    }
    el[idx] = sl;
    er[idx] = sr;
}

__global__ void elr_row_kernel(const float* __restrict__ X, const float* __restrict__ alv,
                               const float* __restrict__ arv, float* __restrict__ el,
                               float* __restrict__ er, int R) {
    int r = blockIdx.x * blockDim.x + threadIdx.x;
    if (r >= R) return;
    const float4* x4 = (const float4*)(X + (size_t)r * 64);
    float sl[8] = {}, sr[8] = {};
    for (int kg = 0; kg < 16; ++kg) {
        float4 xv = x4[kg];
        #pragma unroll
        for (int h = 0; h < 8; ++h) {
            float4 a = *(const float4*)&alv[h * 64 + kg * 4];
            float4 b = *(const float4*)&arv[h * 64 + kg * 4];
            sl[h] = fmaf(xv.x, a.x, fmaf(xv.y, a.y, fmaf(xv.z, a.z, fmaf(xv.w, a.w, sl[h]))));
            sr[h] = fmaf(xv.x, b.x, fmaf(xv.y, b.y, fmaf(xv.z, b.z, fmaf(xv.w, b.w, sr[h]))));
        }
    }
    float* elp = el + (size_t)r * 8;
    float* erp = er + (size_t)r * 8;
    #pragma unroll
    for (int h = 0; h < 8; ++h) { elp[h] = sl[h]; erp[h] = sr[h]; }
}

__device__ __forceinline__ float gelu_exact(float v) {
    return 0.5f * v * (1.0f + erff(v * 0.70710678118654752440f));
}

// ---------------- layer-1 aggregation: wave per (node, head-pair) ----------------
__global__ __launch_bounds__(256) void agg_l1(
    const float* __restrict__ feat, const float* __restrict__ el, const float* __restrict__ er,
    const float* __restrict__ bias, const int* __restrict__ row_ptr,
    const int* __restrict__ csr_src, float* __restrict__ out) {
    int n = blockIdx.x;
    int t = threadIdx.x, wv = t >> 6, lane = t & 63;
    int h0 = 2 * wv;
    int r0 = row_ptr[n], deg = row_ptr[n + 1] - r0;
    float2 erv = *(const float2*)&er[n * 8 + h0];
    float den0 = 0.f, den1 = 0.f, a0 = 0.f, a1 = 0.f;
    for (int i = 0; i < deg; ++i) {
        int s = csr_src[r0 + i];
        float2 elv = *(const float2*)&el[s * 8 + h0];
        float x0 = feat[((size_t)s * 8 + h0) * 64 + lane];
        float x1 = feat[((size_t)s * 8 + h0 + 1) * 64 + lane];
        float e0 = elv.x + erv.x; e0 = e0 > 0.f ? e0 : 0.2f * e0;
        float e1 = elv.y + erv.y; e1 = e1 > 0.f ? e1 : 0.2f * e1;
        float w0 = __expf(e0), w1 = __expf(e1);
        den0 += w0; den1 += w1;
        a0 = fmaf(w0, x0, a0);
        a1 = fmaf(w1, x1, a1);
    }
    float i0 = deg ? 1.f / den0 : 0.f;
    float i1 = deg ? 1.f / den1 : 0.f;
    float v0 = a0 * i0 + bias[h0 * 64 + lane];
    float v1 = a1 * i1 + bias[(h0 + 1) * 64 + lane];
    out[((size_t)n * 8 + h0) * 64 + lane] = gelu_exact(v0);
    out[((size_t)n * 8 + h0 + 1) * 64 + lane] = gelu_exact(v1);
}

// ---------------- layers 2/3: LDS-staged weights + register-blocked transform ----------------
// Occupancy-tuned: KSPLIT=2 both layers; L3 uses FELEM=2 so all 256 threads work in phase T.
// L3 LDS = 35.5 KB -> 4 blocks/CU (16 waves); L2 = 52.7 KB -> 3 blocks/CU.
template <int FOUT, bool GELU, int P>
__global__ __launch_bounds__(256, 4) void agg_fused4(
    const float* __restrict__ X,     // [N*P, 64]
    const float* __restrict__ el, const float* __restrict__ er,  // [N*P, 8]
    const float* __restrict__ W4t,   // [16][8*FOUT][4]
    const float* __restrict__ bias,  // [8*FOUT]
    const int* __restrict__ row_ptr, const int* __restrict__ csr_src,
    float* __restrict__ out)         // [N*P, 8*FOUT]
{
    constexpr int TOT = 8 * FOUT;
    constexpr int KSPLIT = 2;
    constexpr int KGPT = 8;                     // kg per thread (16 kg / KSPLIT)
    constexpr int FELEM = (FOUT == 32) ? 2 : 4; // outputs per thread-column in phase T
    constexpr int FQn = FOUT / FELEM;           // 16 both
    constexpr int TPK = 8 * FQn;                // 128 both -> KSPLIT*TPK = 256 threads
    constexpr int FQ4 = FOUT / 4;
    constexpr int PTS = FOUT + 4;               // padded partial stride
    constexpr int WPFL = (KSPLIT * 64 * PTS > 64 * 64) ? KSPLIT * 64 * PTS : 64 * 64;
    constexpr int GRPS = P / 8;
    constexpr int CHUNK = 64;

    int nb = blockIdx.x;
    int n = nb / GRPS, pg = nb - n * GRPS;
    int p0 = pg * 8;
    int r0 = row_ptr[n], deg = row_ptr[n + 1] - r0;
    int t = threadIdx.x, wv = t >> 6, lane = t & 63;

    __shared__ int src_s[CHUNK];
    __shared__ float inv_s[64];
    __shared__ float acc_s[8][8][68];
    __shared__ float wp_lds[WPFL];   // union: w[i][pl*8+h] (phase W/A) | partials (phase T/R)

    float agg0[8], agg1[8];
    #pragma unroll
    for (int h = 0; h < 8; ++h) { agg0[h] = 0.f; agg1[h] = 0.f; }
    float den = 0.f;  // stat threads t<64: (pl,h) = (t>>3, t&7)

    int elbase_n = (n * P + p0) * 8;
    int pA = p0 + wv * 2;

    for (int c0 = 0; c0 < deg; c0 += CHUNK) {
        int cnt = min(deg - c0, CHUNK);
        __syncthreads();
        if (t < cnt) src_s[t] = csr_src[r0 + c0 + t];
        for (int j = t; j < cnt * 64; j += 256) {
            int i = j >> 6, plh = j & 63;
            int s = csr_src[r0 + c0 + i];
            float e = el[(s * P + p0) * 8 + plh] + er[elbase_n + plh];
            e = e > 0.f ? e : 0.2f * e;
            wp_lds[i * 64 + plh] = __expf(e);
        }
        __syncthreads();
        if (t < 64) {
            for (int i = 0; i < cnt; ++i) den += wp_lds[i * 64 + t];
        }
        // phase A: 2-edge unrolled for load ILP
        auto edge_fma = [&](int i) {
            int s = src_s[i];
            const float* wp = &wp_lds[i * 64 + wv * 16];
            float4 w0 = *(const float4*)wp;
            float4 w1 = *(const float4*)(wp + 4);
            float4 w2 = *(const float4*)(wp + 8);
            float4 w3 = *(const float4*)(wp + 12);
            int xb = (s * P + pA) * 64 + lane;
            float xv0 = X[xb];
            float xv1 = X[xb + 64];
            agg0[0] = fmaf(w0.x, xv0, agg0[0]);
            agg0[1] = fmaf(w0.y, xv0, agg0[1]);
            agg0[2] = fmaf(w0.z, xv0, agg0[2]);
            agg0[3] = fmaf(w0.w, xv0, agg0[3]);
            agg0[4] = fmaf(w1.x, xv0, agg0[4]);
            agg0[5] = fmaf(w1.y, xv0, agg0[5]);
            agg0[6] = fmaf(w1.z, xv0, agg0[6]);
            agg0[7] = fmaf(w1.w, xv0, agg0[7]);
            agg1[0] = fmaf(w2.x, xv1, agg1[0]);
            agg1[1] = fmaf(w2.y, xv1, agg1[1]);
            agg1[2] = fmaf(w2.z, xv1, agg1[2]);
            agg1[3] = fmaf(w2.w, xv1, agg1[3]);
            agg1[4] = fmaf(w3.x, xv1, agg1[4]);
            agg1[5] = fmaf(w3.y, xv1, agg1[5]);
            agg1[6] = fmaf(w3.z, xv1, agg1[6]);
            agg1[7] = fmaf(w3.w, xv1, agg1[7]);
        };
        int i = 0;
        for (; i + 2 <= cnt; i += 2) { edge_fma(i); edge_fma(i + 1); }
        if (i < cnt) edge_fma(i);
    }
    if (t < 64) inv_s[t] = deg ? 1.f / den : 0.f;
    __syncthreads();
    {
        int pl0 = wv * 2;
        #pragma unroll
        for (int h = 0; h < 8; ++h) {
            acc_s[pl0][h][lane] = agg0[h] * inv_s[pl0 * 8 + h];
            acc_s[pl0 + 1][h][lane] = agg1[h] * inv_s[pl0 * 8 + 8 + h];
        }
    }
    __syncthreads();

    // phase T: partial transforms into wp_lds (weights buffer dead now)
    {
        int kq = t / TPK;
        int rem = t - kq * TPK;
        int h = rem / FQn;
        int ft = rem - h * FQn;
        int f0 = ft * FELEM;
        float part[8][FELEM];
        #pragma unroll
        for (int pl = 0; pl < 8; ++pl)
            #pragma unroll
            for (int j = 0; j < FELEM; ++j) part[pl][j] = 0.f;
        #pragma unroll
        for (int kk = 0; kk < KGPT; ++kk) {
            int kg = kq * KGPT + kk;
            float4 wr[FELEM];
            #pragma unroll
            for (int j = 0; j < FELEM; ++j)
                wr[j] = *(const float4*)&W4t[(size_t)(kg * TOT + h * FOUT + f0 + j) * 4];
            #pragma unroll
            for (int pl = 0; pl < 8; ++pl) {
                float4 a4 = *(const float4*)&acc_s[pl][h][kg * 4];
                #pragma unroll
                for (int j = 0; j < FELEM; ++j)
                    part[pl][j] = fmaf(a4.x, wr[j].x, fmaf(a4.y, wr[j].y,
                                  fmaf(a4.z, wr[j].z, fmaf(a4.w, wr[j].w, part[pl][j]))));
            }
        }
        #pragma unroll
        for (int pl = 0; pl < 8; ++pl) {
            float* dstp = &wp_lds[((kq * 8 + pl) * 8 + h) * PTS + f0];
            if (FELEM == 4)
                *(float4*)dstp = make_float4(part[pl][0], part[pl][1], part[pl][2], part[pl][3]);
            else
                *(float2*)dstp = make_float2(part[pl][0], part[pl][1]);
        }
    }
    __syncthreads();

    // phase R: reduce KSPLIT partials, bias, (gelu), store (float4 granularity)
    {
        constexpr int NQ = 2 * TOT;          // 8 pl * (TOT/4) quads
        for (int q = t; q < NQ; q += 256) {
            int pl = q / (TOT / 4);
            int rem = q - pl * (TOT / 4);
            int h = rem / FQ4, fq = rem - h * FQ4;
            int f0 = fq * 4;
            float4 acc4 = *(const float4*)&wp_lds[((0 * 8 + pl) * 8 + h) * PTS + f0];
            #pragma unroll
            for (int kq = 1; kq < KSPLIT; ++kq) {
                float4 pv = *(const float4*)&wp_lds[((kq * 8 + pl) * 8 + h) * PTS + f0];
                acc4.x += pv.x; acc4.y += pv.y; acc4.z += pv.z; acc4.w += pv.w;
            }
            float4 b4 = *(const float4*)&bias[h * FOUT + f0];
            acc4.x += b4.x; acc4.y += b4.y; acc4.z += b4.z; acc4.w += b4.w;
            if (GELU) {
                acc4.x = gelu_exact(acc4.x); acc4.y = gelu_exact(acc4.y);
                acc4.z = gelu_exact(acc4.z); acc4.w = gelu_exact(acc4.w);
            }
            *(float4*)&out[(size_t)(n * P + p0 + pl) * TOT + h * FOUT + f0] = acc4;
        }
    }
}

// ---------------- launch ----------------

extern "C" void kernel_launch(void* const* d_in, const int* in_sizes, int n_in,
                              void* d_out, int out_size, void* d_ws, size_t ws_size,
                              hipStream_t stream) {
    const float* node = (const float*)d_in[0];
    const int* src = (const int*)d_in[1];
    const int* dst = (const int*)d_in[2];
    const float* W1 = (const float*)d_in[3];
    const float* al1 = (const float*)d_in[4];
    const float* ar1 = (const float*)d_in[5];
    const float* b1 = (const float*)d_in[6];
    const float* W2 = (const float*)d_in[7];
    const float* al2 = (const float*)d_in[8];
    const float* ar2 = (const float*)d_in[9];
    const float* b2 = (const float*)d_in[10];
    const float* W3 = (const float*)d_in[11];
    const float* al3 = (const float*)d_in[12];
    const float* ar3 = (const float*)d_in[13];
    const float* b3 = (const float*)d_in[14];
    float* out = (float*)d_out;

    char* ws = (char*)d_ws;
    size_t off = 0;
    auto alloc = [&](size_t nb) -> char* {
        char* q = ws + off;
        off += (nb + 255) & ~(size_t)255;
        return q;
    };
    int* counts   = (int*)alloc((N_NODES + 1) * sizeof(int));
    int* row_ptr  = (int*)alloc((N_NODES + 1) * sizeof(int));
    int* csr_src  = (int*)alloc(N_EDGES * sizeof(int));
    float* feat1  = (float*)alloc((size_t)N_NODES * 8 * 64 * 4);
    float* el1    = (float*)alloc((size_t)N_NODES * 8 * 4);
    float* er1    = (float*)alloc((size_t)N_NODES * 8 * 4);
    float* h1     = (float*)alloc((size_t)N_NODES * 8 * 64 * 4);
    float* aleff2 = (float*)alloc(8 * 64 * 4);
    float* areff2 = (float*)alloc(8 * 64 * 4);
    float* el2    = (float*)alloc((size_t)N_NODES * 8 * 8 * 4);
    float* er2    = (float*)alloc((size_t)N_NODES * 8 * 8 * 4);
    float* h2     = (float*)alloc((size_t)N_NODES * 64 * 64 * 4);
    float* aleff3 = (float*)alloc(8 * 64 * 4);
    float* areff3 = (float*)alloc(8 * 64 * 4);
    float* el3    = (float*)alloc((size_t)N_NODES * 64 * 8 * 4);
    float* er3    = (float*)alloc((size_t)N_NODES * 64 * 8 * 4);
    float* W4t2   = (float*)alloc((size_t)16 * 512 * 4 * 4);
    float* W4t3   = (float*)alloc((size_t)16 * 256 * 4 * 4);

    const int PREP_T = 1536 + 1024 + 1024 + 16 * 512 * 4 + 16 * 256 * 4;
    prep_kernel<<<(PREP_T + 255) / 256, 256, 0, stream>>>(
        W2, al2, ar2, W3, al3, ar3, aleff2, areff2, aleff3, areff3, W4t2, W4t3, counts);

    hist_kernel<<<(N_EDGES + 255) / 256, 256, 0, stream>>>(dst, counts);
    scan_kernel<<<1, 256, 0, stream>>>(counts, row_ptr);
    build_csr_kernel<<<(N_NODES * 64 + 255) / 256, 256, 0, stream>>>(dst, src, row_ptr, csr_src);

    // ---- layer 1 ----
    dim3 g1(512 / BN, (N_NODES + BM - 1) / BM);
    gemm_f32<<<g1, 256, 0, stream>>>(node, W1, feat1, N_NODES, 512, IN_FEAT);
    elr_feat_kernel<<<(N_NODES * 8 + 255) / 256, 256, 0, stream>>>(feat1, al1, ar1, el1, er1, N_NODES * 8);
    agg_l1<<<N_NODES, 256, 0, stream>>>(feat1, el1, er1, b1, row_ptr, csr_src, h1);

    // ---- layer 2 ----
    elr_row_kernel<<<(N_NODES * 8 + 255) / 256, 256, 0, stream>>>(h1, aleff2, areff2, el2, er2, N_NODES * 8);
    agg_fused4<64, true, 8><<<N_NODES, 256, 0, stream>>>(h1, el2, er2, W4t2, b2, row_ptr, csr_src, h2);

    // ---- layer 3 ----
    elr_row_kernel<<<(N_NODES * 64 + 255) / 256, 256, 0, stream>>>(h2, aleff3, areff3, el3, er3, N_NODES * 64);
    agg_fused4<32, false, 64><<<N_NODES * 8, 256, 0, stream>>>(h2, el3, er3, W4t3, b3, row_ptr, csr_src, out);
}

// Round 6
// 237.636 us; speedup vs baseline: 4.4501x; 1.0641x over previous
//
#include <hip/hip_runtime.h>
#include <math.h>

#define N_NODES 1500
#define N_EDGES 12000
#define IN_FEAT 512
#define HIDDEN 64
#define OUT_FEAT 32
#define HEADS 8

typedef short bf16x8 __attribute__((ext_vector_type(8)));
typedef float f32x4 __attribute__((ext_vector_type(4)));

__device__ __forceinline__ unsigned short f2bf(float f) {
    unsigned u = __float_as_uint(f);
    u += 0x7fff + ((u >> 16) & 1);   // RNE
    return (unsigned short)(u >> 16);
}
__device__ __forceinline__ float bf2f(unsigned short b) {
    return __uint_as_float(((unsigned)b) << 16);
}
__device__ __forceinline__ unsigned packbf(float a) {
    unsigned short hi = f2bf(a);
    unsigned short lo = f2bf(a - bf2f(hi));
    return (unsigned)hi | ((unsigned)lo << 16);
}

// ---------------- fused prep: counts + att-eff vectors + W2 reshuffle + W3 MFMA frags ----
// W4t2 layout: W4t2[(kg*512 + c)*4 + j] = W2[(kg*4+j)*512 + c]
// wfrag3 layout: [(h*2+nt)*2+ks][lane][j] -> packed bf16 hi|lo of W3[ks*32+(l>>4)*8+j][h*32+nt*16+(l&15)]

__global__ void prep_kernel(const float* __restrict__ W2, const float* __restrict__ al2,
                            const float* __restrict__ ar2,
                            const float* __restrict__ W3, const float* __restrict__ al3,
                            const float* __restrict__ ar3,
                            float* __restrict__ aleff2, float* __restrict__ areff2,
                            float* __restrict__ aleff3, float* __restrict__ areff3,
                            float* __restrict__ W4t2, unsigned* __restrict__ wfrag3,
                            int* __restrict__ counts) {
    int i = blockIdx.x * blockDim.x + threadIdx.x;
    if (i < 1536) {
        if (i < N_NODES + 1) counts[i] = 0;
        return;
    }
    i -= 1536;
    if (i < 1024) {  // aleff2 / areff2: [h][64]
        int lr = i >> 9; i &= 511;
        int h = i >> 6, k = i & 63;
        const float* a = lr ? ar2 : al2;
        float s = 0.f;
        for (int f = 0; f < 64; ++f)
            s = fmaf(W2[(size_t)k * 512 + h * 64 + f], a[h * 64 + f], s);
        (lr ? areff2 : aleff2)[h * 64 + k] = s;
        return;
    }
    i -= 1024;
    if (i < 1024) {  // aleff3 / areff3
        int lr = i >> 9; i &= 511;
        int h = i >> 6, k = i & 63;
        const float* a = lr ? ar3 : al3;
        float s = 0.f;
        for (int f = 0; f < 32; ++f)
            s = fmaf(W3[(size_t)k * 256 + h * 32 + f], a[h * 32 + f], s);
        (lr ? areff3 : aleff3)[h * 64 + k] = s;
        return;
    }
    i -= 1024;
    if (i < 16 * 512 * 4) {  // W4t2
        int kg = i >> 11, rem = i & 2047;
        int c = rem >> 2, j = rem & 3;
        W4t2[i] = W2[(size_t)(kg * 4 + j) * 512 + c];
        return;
    }
    i -= 16 * 512 * 4;
    if (i < 16384) {  // wfrag3 (B-fragments for mfma_f32_16x16x32_bf16, hi/lo packed)
        int j = i & 7, l = (i >> 3) & 63;
        int ks = (i >> 9) & 1, nt = (i >> 10) & 1, h = (i >> 11) & 7;
        int k = ks * 32 + (l >> 4) * 8 + j;
        int col = h * 32 + nt * 16 + (l & 15);
        wfrag3[i] = packbf(W3[(size_t)k * 256 + col]);
    }
}

__global__ void hist_kernel(const int* __restrict__ dst, int* __restrict__ counts) {
    int e = blockIdx.x * blockDim.x + threadIdx.x;
    if (e < N_EDGES) atomicAdd(&counts[dst[e]], 1);
}

__global__ void scan_kernel(const int* __restrict__ counts, int* __restrict__ row_ptr) {
    __shared__ int part[256];
    int t = threadIdx.x;
    const int CH = (N_NODES + 255) / 256;
    int base = t * CH;
    int loc[8];
    int s = 0;
    for (int i = 0; i < CH; ++i) {
        int idx = base + i;
        int v = (idx < N_NODES) ? counts[idx] : 0;
        loc[i] = s;
        s += v;
    }
    part[t] = s;
    __syncthreads();
    if (t == 0) {
        int a = 0;
        for (int i = 0; i < 256; ++i) { int v = part[i]; part[i] = a; a += v; }
        row_ptr[N_NODES] = a;
    }
    __syncthreads();
    int p0 = part[t];
    for (int i = 0; i < CH; ++i) {
        int idx = base + i;
        if (idx < N_NODES) row_ptr[idx] = p0 + loc[i];
    }
}

// wave-per-node stable CSR build; stores SRC NODE ID directly.
__global__ void build_csr_kernel(const int* __restrict__ dst, const int* __restrict__ src,
                                 const int* __restrict__ row_ptr, int* __restrict__ csr_src) {
    int wid = (blockIdx.x * blockDim.x + threadIdx.x) >> 6;
    int lane = threadIdx.x & 63;
    if (wid >= N_NODES) return;
    int pos = row_ptr[wid];
    for (int base = 0; base < N_EDGES; base += 64) {
        int e = base + lane;
        bool hit = (e < N_EDGES) && (dst[e] == wid);
        unsigned long long m = __ballot(hit);
        if (hit) {
            int r = __popcll(m & ((1ull << lane) - 1ull));
            csr_src[pos + r] = src[e];
        }
        pos += __popcll(m);
    }
}

// ---------------- f32 tiled GEMM (layer 1): BK=32, register prefetch ----------------

#define BM 64
#define BN 64
#define BK2 32

__global__ __launch_bounds__(256) void gemm_f32(const float* __restrict__ A,
                                                const float* __restrict__ B,
                                                float* __restrict__ C,
                                                int M, int N, int K) {
    __shared__ float As[BK2][BM + 4];
    __shared__ float Bs[BK2][BN + 4];
    int t = threadIdx.x;
    int col0 = blockIdx.x * BN, row0 = blockIdx.y * BM;
    int tx = t & 15, ty = t >> 4;
    int am = t >> 3, ak = (t & 7) * 4;
    int bk = t >> 4, bn = (t & 15) * 4;
    float4 pa[2], pb[2];
    auto load_tile = [&](int k0) {
        #pragma unroll
        for (int i = 0; i < 2; ++i) {
            int gr = row0 + am + 32 * i;
            pa[i] = (gr < M) ? *(const float4*)&A[(size_t)gr * K + k0 + ak]
                             : make_float4(0.f, 0.f, 0.f, 0.f);
            pb[i] = *(const float4*)&B[(size_t)(k0 + bk + 16 * i) * N + col0 + bn];
        }
    };
    load_tile(0);
    float acc[4][4] = {};
    for (int k0 = 0; k0 < K; k0 += BK2) {
        __syncthreads();
        #pragma unroll
        for (int i = 0; i < 2; ++i) {
            As[ak + 0][am + 32 * i] = pa[i].x;
            As[ak + 1][am + 32 * i] = pa[i].y;
            As[ak + 2][am + 32 * i] = pa[i].z;
            As[ak + 3][am + 32 * i] = pa[i].w;
            *(float4*)&Bs[bk + 16 * i][bn] = pb[i];
        }
        __syncthreads();
        if (k0 + BK2 < K) load_tile(k0 + BK2);
        #pragma unroll
        for (int kk = 0; kk < BK2; ++kk) {
            float4 a4 = *(const float4*)&As[kk][ty * 4];
            float4 b4 = *(const float4*)&Bs[kk][tx * 4];
            float av[4] = {a4.x, a4.y, a4.z, a4.w};
            float bv[4] = {b4.x, b4.y, b4.z, b4.w};
            #pragma unroll
            for (int i = 0; i < 4; ++i)
                #pragma unroll
                for (int j = 0; j < 4; ++j)
                    acc[i][j] = fmaf(av[i], bv[j], acc[i][j]);
        }
    }
    #pragma unroll
    for (int i = 0; i < 4; ++i) {
        int gr = row0 + ty * 4 + i;
        if (gr < M) {
            float4 v = make_float4(acc[i][0], acc[i][1], acc[i][2], acc[i][3]);
            *(float4*)&C[(size_t)gr * N + col0 + tx * 4] = v;
        }
    }
}

// ---------------- el/er kernels ----------------

__global__ void elr_feat_kernel(const float* __restrict__ feat, const float* __restrict__ al,
                                const float* __restrict__ ar, float* __restrict__ el,
                                float* __restrict__ er, int RH) {
    int idx = blockIdx.x * blockDim.x + threadIdx.x;
    if (idx >= RH) return;
    int h = idx & (HEADS - 1);
    const float* fp = feat + (size_t)idx * HIDDEN;
    float sl = 0.f, sr = 0.f;
    for (int f = 0; f < HIDDEN; ++f) {
        float v = fp[f];
        sl = fmaf(v, al[h * HIDDEN + f], sl);
        sr = fmaf(v, ar[h * HIDDEN + f], sr);
    }
    el[idx] = sl;
    er[idx] = sr;
}

__global__ void elr_row_kernel(const float* __restrict__ X, const float* __restrict__ alv,
                               const float* __restrict__ arv, float* __restrict__ el,
                               float* __restrict__ er, int R) {
    int r = blockIdx.x * blockDim.x + threadIdx.x;
    if (r >= R) return;
    const float4* x4 = (const float4*)(X + (size_t)r * 64);
    float sl[8] = {}, sr[8] = {};
    for (int kg = 0; kg < 16; ++kg) {
        float4 xv = x4[kg];
        #pragma unroll
        for (int h = 0; h < 8; ++h) {
            float4 a = *(const float4*)&alv[h * 64 + kg * 4];
            float4 b = *(const float4*)&arv[h * 64 + kg * 4];
            sl[h] = fmaf(xv.x, a.x, fmaf(xv.y, a.y, fmaf(xv.z, a.z, fmaf(xv.w, a.w, sl[h]))));
            sr[h] = fmaf(xv.x, b.x, fmaf(xv.y, b.y, fmaf(xv.z, b.z, fmaf(xv.w, b.w, sr[h]))));
        }
    }
    float* elp = el + (size_t)r * 8;
    float* erp = er + (size_t)r * 8;
    #pragma unroll
    for (int h = 0; h < 8; ++h) { elp[h] = sl[h]; erp[h] = sr[h]; }
}

__device__ __forceinline__ float gelu_exact(float v) {
    return 0.5f * v * (1.0f + erff(v * 0.70710678118654752440f));
}

// ---------------- layer-1 aggregation: wave per (node, head-pair) ----------------
__global__ __launch_bounds__(256) void agg_l1(
    const float* __restrict__ feat, const float* __restrict__ el, const float* __restrict__ er,
    const float* __restrict__ bias, const int* __restrict__ row_ptr,
    const int* __restrict__ csr_src, float* __restrict__ out) {
    int n = blockIdx.x;
    int t = threadIdx.x, wv = t >> 6, lane = t & 63;
    int h0 = 2 * wv;
    int r0 = row_ptr[n], deg = row_ptr[n + 1] - r0;
    float2 erv = *(const float2*)&er[n * 8 + h0];
    float den0 = 0.f, den1 = 0.f, a0 = 0.f, a1 = 0.f;
    for (int i = 0; i < deg; ++i) {
        int s = csr_src[r0 + i];
        float2 elv = *(const float2*)&el[s * 8 + h0];
        float x0 = feat[((size_t)s * 8 + h0) * 64 + lane];
        float x1 = feat[((size_t)s * 8 + h0 + 1) * 64 + lane];
        float e0 = elv.x + erv.x; e0 = e0 > 0.f ? e0 : 0.2f * e0;
        float e1 = elv.y + erv.y; e1 = e1 > 0.f ? e1 : 0.2f * e1;
        float w0 = __expf(e0), w1 = __expf(e1);
        den0 += w0; den1 += w1;
        a0 = fmaf(w0, x0, a0);
        a1 = fmaf(w1, x1, a1);
    }
    float i0 = deg ? 1.f / den0 : 0.f;
    float i1 = deg ? 1.f / den1 : 0.f;
    float v0 = a0 * i0 + bias[h0 * 64 + lane];
    float v1 = a1 * i1 + bias[(h0 + 1) * 64 + lane];
    out[((size_t)n * 8 + h0) * 64 + lane] = gelu_exact(v0);
    out[((size_t)n * 8 + h0 + 1) * 64 + lane] = gelu_exact(v1);
}

// ---------------- layer 2: LDS-staged weights + register-blocked transform ----------------
template <int FOUT, bool GELU, int P>
__global__ __launch_bounds__(256, 4) void agg_fused4(
    const float* __restrict__ X,
    const float* __restrict__ el, const float* __restrict__ er,
    const float* __restrict__ W4t,
    const float* __restrict__ bias,
    const int* __restrict__ row_ptr, const int* __restrict__ csr_src,
    float* __restrict__ out)
{
    constexpr int TOT = 8 * FOUT;
    constexpr int KSPLIT = 2;
    constexpr int KGPT = 8;
    constexpr int FELEM = (FOUT == 32) ? 2 : 4;
    constexpr int FQn = FOUT / FELEM;
    constexpr int TPK = 8 * FQn;
    constexpr int FQ4 = FOUT / 4;
    constexpr int PTS = FOUT + 4;
    constexpr int WPFL = (KSPLIT * 64 * PTS > 64 * 64) ? KSPLIT * 64 * PTS : 64 * 64;
    constexpr int GRPS = P / 8;
    constexpr int CHUNK = 64;

    int nb = blockIdx.x;
    int n = nb / GRPS, pg = nb - n * GRPS;
    int p0 = pg * 8;
    int r0 = row_ptr[n], deg = row_ptr[n + 1] - r0;
    int t = threadIdx.x, wv = t >> 6, lane = t & 63;

    __shared__ int src_s[CHUNK];
    __shared__ float inv_s[64];
    __shared__ float acc_s[8][8][68];
    __shared__ float wp_lds[WPFL];

    float agg0[8], agg1[8];
    #pragma unroll
    for (int h = 0; h < 8; ++h) { agg0[h] = 0.f; agg1[h] = 0.f; }
    float den = 0.f;

    int elbase_n = (n * P + p0) * 8;
    int pA = p0 + wv * 2;

    for (int c0 = 0; c0 < deg; c0 += CHUNK) {
        int cnt = min(deg - c0, CHUNK);
        __syncthreads();
        if (t < cnt) src_s[t] = csr_src[r0 + c0 + t];
        for (int j = t; j < cnt * 64; j += 256) {
            int i = j >> 6, plh = j & 63;
            int s = csr_src[r0 + c0 + i];
            float e = el[(s * P + p0) * 8 + plh] + er[elbase_n + plh];
            e = e > 0.f ? e : 0.2f * e;
            wp_lds[i * 64 + plh] = __expf(e);
        }
        __syncthreads();
        if (t < 64) {
            for (int i = 0; i < cnt; ++i) den += wp_lds[i * 64 + t];
        }
        auto edge_fma = [&](int i) {
            int s = src_s[i];
            const float* wp = &wp_lds[i * 64 + wv * 16];
            float4 w0 = *(const float4*)wp;
            float4 w1 = *(const float4*)(wp + 4);
            float4 w2 = *(const float4*)(wp + 8);
            float4 w3 = *(const float4*)(wp + 12);
            int xb = (s * P + pA) * 64 + lane;
            float xv0 = X[xb];
            float xv1 = X[xb + 64];
            agg0[0] = fmaf(w0.x, xv0, agg0[0]);
            agg0[1] = fmaf(w0.y, xv0, agg0[1]);
            agg0[2] = fmaf(w0.z, xv0, agg0[2]);
            agg0[3] = fmaf(w0.w, xv0, agg0[3]);
            agg0[4] = fmaf(w1.x, xv0, agg0[4]);
            agg0[5] = fmaf(w1.y, xv0, agg0[5]);
            agg0[6] = fmaf(w1.z, xv0, agg0[6]);
            agg0[7] = fmaf(w1.w, xv0, agg0[7]);
            agg1[0] = fmaf(w2.x, xv1, agg1[0]);
            agg1[1] = fmaf(w2.y, xv1, agg1[1]);
            agg1[2] = fmaf(w2.z, xv1, agg1[2]);
            agg1[3] = fmaf(w2.w, xv1, agg1[3]);
            agg1[4] = fmaf(w3.x, xv1, agg1[4]);
            agg1[5] = fmaf(w3.y, xv1, agg1[5]);
            agg1[6] = fmaf(w3.z, xv1, agg1[6]);
            agg1[7] = fmaf(w3.w, xv1, agg1[7]);
        };
        int i = 0;
        for (; i + 2 <= cnt; i += 2) { edge_fma(i); edge_fma(i + 1); }
        if (i < cnt) edge_fma(i);
    }
    if (t < 64) inv_s[t] = deg ? 1.f / den : 0.f;
    __syncthreads();
    {
        int pl0 = wv * 2;
        #pragma unroll
        for (int h = 0; h < 8; ++h) {
            acc_s[pl0][h][lane] = agg0[h] * inv_s[pl0 * 8 + h];
            acc_s[pl0 + 1][h][lane] = agg1[h] * inv_s[pl0 * 8 + 8 + h];
        }
    }
    __syncthreads();

    {
        int kq = t / TPK;
        int rem = t - kq * TPK;
        int h = rem / FQn;
        int ft = rem - h * FQn;
        int f0 = ft * FELEM;
        float part[8][FELEM];
        #pragma unroll
        for (int pl = 0; pl < 8; ++pl)
            #pragma unroll
            for (int j = 0; j < FELEM; ++j) part[pl][j] = 0.f;
        #pragma unroll
        for (int kk = 0; kk < KGPT; ++kk) {
            int kg = kq * KGPT + kk;
            float4 wr[FELEM];
            #pragma unroll
            for (int j = 0; j < FELEM; ++j)
                wr[j] = *(const float4*)&W4t[(size_t)(kg * TOT + h * FOUT + f0 + j) * 4];
            #pragma unroll
            for (int pl = 0; pl < 8; ++pl) {
                float4 a4 = *(const float4*)&acc_s[pl][h][kg * 4];
                #pragma unroll
                for (int j = 0; j < FELEM; ++j)
                    part[pl][j] = fmaf(a4.x, wr[j].x, fmaf(a4.y, wr[j].y,
                                  fmaf(a4.z, wr[j].z, fmaf(a4.w, wr[j].w, part[pl][j]))));
            }
        }
        #pragma unroll
        for (int pl = 0; pl < 8; ++pl) {
            float* dstp = &wp_lds[((kq * 8 + pl) * 8 + h) * PTS + f0];
            if (FELEM == 4)
                *(float4*)dstp = make_float4(part[pl][0], part[pl][1], part[pl][2], part[pl][3]);
            else
                *(float2*)dstp = make_float2(part[pl][0], part[pl][1]);
        }
    }
    __syncthreads();

    {
        constexpr int NQ = 2 * TOT;
        for (int q = t; q < NQ; q += 256) {
            int pl = q / (TOT / 4);
            int rem = q - pl * (TOT / 4);
            int h = rem / FQ4, fq = rem - h * FQ4;
            int f0 = fq * 4;
            float4 acc4 = *(const float4*)&wp_lds[((0 * 8 + pl) * 8 + h) * PTS + f0];
            #pragma unroll
            for (int kq = 1; kq < KSPLIT; ++kq) {
                float4 pv = *(const float4*)&wp_lds[((kq * 8 + pl) * 8 + h) * PTS + f0];
                acc4.x += pv.x; acc4.y += pv.y; acc4.z += pv.z; acc4.w += pv.w;
            }
            float4 b4 = *(const float4*)&bias[h * FOUT + f0];
            acc4.x += b4.x; acc4.y += b4.y; acc4.z += b4.z; acc4.w += b4.w;
            if (GELU) {
                acc4.x = gelu_exact(acc4.x); acc4.y = gelu_exact(acc4.y);
                acc4.z = gelu_exact(acc4.z); acc4.w = gelu_exact(acc4.w);
            }
            *(float4*)&out[(size_t)(n * P + p0 + pl) * TOT + h * FOUT + f0] = acc4;
        }
    }
}

// ---------------- layer 3: aggregation + MFMA transform (bf16 hi/lo split) ----------------
// Block = (node, 16-p group). acc[16p][8h][64k] packed (bf16hi | bf16lo<<16) in LDS;
// transform D[16p x 32f] per head via mfma_f32_16x16x32_bf16 x3 (hi*hi + hi*lo + lo*hi).
__global__ __launch_bounds__(256, 3) void agg_mfma3(
    const float* __restrict__ X,        // h2 [N*64, 64]
    const float* __restrict__ el, const float* __restrict__ er,  // [N*64, 8]
    const unsigned* __restrict__ wfrag, // [8h][2nt][2ks][64l][8j]
    const float* __restrict__ bias,     // [256]
    const int* __restrict__ row_ptr, const int* __restrict__ csr_src,
    float* __restrict__ out)            // [N*64, 256]
{
    constexpr int CHUNK = 32;
    int nb = blockIdx.x;                 // N_NODES * 4
    int n = nb >> 2, pg = nb & 3;
    int p0 = pg * 16;
    int r0 = row_ptr[n], deg = row_ptr[n + 1] - r0;
    int t = threadIdx.x, wv = t >> 6, lane = t & 63;

    __shared__ int src_s[CHUNK];
    __shared__ float w_s[CHUNK][128];      // [edge][pl*8+h]
    __shared__ float inv_s[128];
    __shared__ float er_s[128];
    __shared__ unsigned accP[8][16][68];   // [h][pl][k], pl-stride 68 u32 (17x16B: conflict-free)

    if (t < 128) er_s[t] = er[(size_t)(n * 64 + p0 + (t >> 3)) * 8 + (t & 7)];

    float den = 0.f;                       // t<128: (pl,h) = (t>>3, t&7)
    float agg[4][8];
    #pragma unroll
    for (int q = 0; q < 4; ++q)
        #pragma unroll
        for (int h = 0; h < 8; ++h) agg[q][h] = 0.f;
    int pA = p0 + wv * 4;

    for (int c0 = 0; c0 < deg; c0 += CHUNK) {
        int cnt = min(deg - c0, CHUNK);
        __syncthreads();
        if (t < cnt) src_s[t] = csr_src[r0 + c0 + t];
        for (int j = t; j < cnt * 128; j += 256) {
            int i = j >> 7, plh = j & 127;
            int s = csr_src[r0 + c0 + i];
            float e = el[(size_t)(s * 64 + p0) * 8 + plh] + er_s[plh];
            e = e > 0.f ? e : 0.2f * e;
            w_s[i][plh] = __expf(e);
        }
        __syncthreads();
        if (t < 128) {
            for (int i = 0; i < cnt; ++i) den += w_s[i][t];
        }
        for (int i = 0; i < cnt; ++i) {
            int s = src_s[i];
            const float* wp = &w_s[i][wv * 32];
            int xb = (s * 64 + pA) * 64 + lane;
            #pragma unroll
            for (int q = 0; q < 4; ++q) {
                float xv = X[xb + q * 64];
                float4 wa = *(const float4*)(wp + q * 8);
                float4 wb = *(const float4*)(wp + q * 8 + 4);
                agg[q][0] = fmaf(wa.x, xv, agg[q][0]);
                agg[q][1] = fmaf(wa.y, xv, agg[q][1]);
                agg[q][2] = fmaf(wa.z, xv, agg[q][2]);
                agg[q][3] = fmaf(wa.w, xv, agg[q][3]);
                agg[q][4] = fmaf(wb.x, xv, agg[q][4]);
                agg[q][5] = fmaf(wb.y, xv, agg[q][5]);
                agg[q][6] = fmaf(wb.z, xv, agg[q][6]);
                agg[q][7] = fmaf(wb.w, xv, agg[q][7]);
            }
        }
    }
    if (t < 128) inv_s[t] = deg ? 1.f / den : 0.f;
    __syncthreads();

    // scale + convert to packed bf16 hi/lo, write accP
    #pragma unroll
    for (int q = 0; q < 4; ++q) {
        int pl = wv * 4 + q;
        #pragma unroll
        for (int h = 0; h < 8; ++h) {
            float a = agg[q][h] * inv_s[pl * 8 + h];
            accP[h][pl][lane] = packbf(a);
        }
    }
    __syncthreads();

    // MFMA transform: wave wv handles heads 2wv, 2wv+1
    int m16 = lane & 15, g = lane >> 4;
    #pragma unroll
    for (int hh = 0; hh < 2; ++hh) {
        int h = wv * 2 + hh;
        bf16x8 a_hi[2], a_lo[2];
        #pragma unroll
        for (int ks = 0; ks < 2; ++ks) {
            const unsigned* ap = &accP[h][m16][ks * 32 + g * 8];
            uint4 q0 = *(const uint4*)ap;
            uint4 q1 = *(const uint4*)(ap + 4);
            a_hi[ks][0] = (short)(q0.x & 0xffffu); a_lo[ks][0] = (short)(q0.x >> 16);
            a_hi[ks][1] = (short)(q0.y & 0xffffu); a_lo[ks][1] = (short)(q0.y >> 16);
            a_hi[ks][2] = (short)(q0.z & 0xffffu); a_lo[ks][2] = (short)(q0.z >> 16);
            a_hi[ks][3] = (short)(q0.w & 0xffffu); a_lo[ks][3] = (short)(q0.w >> 16);
            a_hi[ks][4] = (short)(q1.x & 0xffffu); a_lo[ks][4] = (short)(q1.x >> 16);
            a_hi[ks][5] = (short)(q1.y & 0xffffu); a_lo[ks][5] = (short)(q1.y >> 16);
            a_hi[ks][6] = (short)(q1.z & 0xffffu); a_lo[ks][6] = (short)(q1.z >> 16);
            a_hi[ks][7] = (short)(q1.w & 0xffffu); a_lo[ks][7] = (short)(q1.w >> 16);
        }
        #pragma unroll
        for (int nt = 0; nt < 2; ++nt) {
            f32x4 D = {0.f, 0.f, 0.f, 0.f};
            #pragma unroll
            for (int ks = 0; ks < 2; ++ks) {
                const unsigned* bp = &wfrag[(size_t)(((h * 2 + nt) * 2 + ks) * 64 + lane) * 8];
                uint4 w0 = *(const uint4*)bp;
                uint4 w1 = *(const uint4*)(bp + 4);
                bf16x8 b_hi, b_lo;
                b_hi[0] = (short)(w0.x & 0xffffu); b_lo[0] = (short)(w0.x >> 16);
                b_hi[1] = (short)(w0.y & 0xffffu); b_lo[1] = (short)(w0.y >> 16);
                b_hi[2] = (short)(w0.z & 0xffffu); b_lo[2] = (short)(w0.z >> 16);
                b_hi[3] = (short)(w0.w & 0xffffu); b_lo[3] = (short)(w0.w >> 16);
                b_hi[4] = (short)(w1.x & 0xffffu); b_lo[4] = (short)(w1.x >> 16);
                b_hi[5] = (short)(w1.y & 0xffffu); b_lo[5] = (short)(w1.y >> 16);
                b_hi[6] = (short)(w1.z & 0xffffu); b_lo[6] = (short)(w1.z >> 16);
                b_hi[7] = (short)(w1.w & 0xffffu); b_lo[7] = (short)(w1.w >> 16);
                D = __builtin_amdgcn_mfma_f32_16x16x32_bf16(a_hi[ks], b_hi, D, 0, 0, 0);
                D = __builtin_amdgcn_mfma_f32_16x16x32_bf16(a_hi[ks], b_lo, D, 0, 0, 0);
                D = __builtin_amdgcn_mfma_f32_16x16x32_bf16(a_lo[ks], b_hi, D, 0, 0, 0);
            }
            float bv = bias[h * 32 + nt * 16 + m16];
            size_t ob = ((size_t)(n * 64) + p0 + g * 4) * 256 + h * 32 + nt * 16 + m16;
            out[ob]       = D[0] + bv;
            out[ob + 256] = D[1] + bv;
            out[ob + 512] = D[2] + bv;
            out[ob + 768] = D[3] + bv;
        }
    }
}

// ---------------- launch ----------------

extern "C" void kernel_launch(void* const* d_in, const int* in_sizes, int n_in,
                              void* d_out, int out_size, void* d_ws, size_t ws_size,
                              hipStream_t stream) {
    const float* node = (const float*)d_in[0];
    const int* src = (const int*)d_in[1];
    const int* dst = (const int*)d_in[2];
    const float* W1 = (const float*)d_in[3];
    const float* al1 = (const float*)d_in[4];
    const float* ar1 = (const float*)d_in[5];
    const float* b1 = (const float*)d_in[6];
    const float* W2 = (const float*)d_in[7];
    const float* al2 = (const float*)d_in[8];
    const float* ar2 = (const float*)d_in[9];
    const float* b2 = (const float*)d_in[10];
    const float* W3 = (const float*)d_in[11];
    const float* al3 = (const float*)d_in[12];
    const float* ar3 = (const float*)d_in[13];
    const float* b3 = (const float*)d_in[14];
    float* out = (float*)d_out;

    char* ws = (char*)d_ws;
    size_t off = 0;
    auto alloc = [&](size_t nb) -> char* {
        char* q = ws + off;
        off += (nb + 255) & ~(size_t)255;
        return q;
    };
    int* counts   = (int*)alloc((N_NODES + 1) * sizeof(int));
    int* row_ptr  = (int*)alloc((N_NODES + 1) * sizeof(int));
    int* csr_src  = (int*)alloc(N_EDGES * sizeof(int));
    float* feat1  = (float*)alloc((size_t)N_NODES * 8 * 64 * 4);
    float* el1    = (float*)alloc((size_t)N_NODES * 8 * 4);
    float* er1    = (float*)alloc((size_t)N_NODES * 8 * 4);
    float* h1     = (float*)alloc((size_t)N_NODES * 8 * 64 * 4);
    float* aleff2 = (float*)alloc(8 * 64 * 4);
    float* areff2 = (float*)alloc(8 * 64 * 4);
    float* el2    = (float*)alloc((size_t)N_NODES * 8 * 8 * 4);
    float* er2    = (float*)alloc((size_t)N_NODES * 8 * 8 * 4);
    float* h2     = (float*)alloc((size_t)N_NODES * 64 * 64 * 4);
    float* aleff3 = (float*)alloc(8 * 64 * 4);
    float* areff3 = (float*)alloc(8 * 64 * 4);
    float* el3    = (float*)alloc((size_t)N_NODES * 64 * 8 * 4);
    float* er3    = (float*)alloc((size_t)N_NODES * 64 * 8 * 4);
    float* W4t2   = (float*)alloc((size_t)16 * 512 * 4 * 4);
    unsigned* wfrag3 = (unsigned*)alloc((size_t)16384 * 4);

    const int PREP_T = 1536 + 1024 + 1024 + 16 * 512 * 4 + 16384;
    prep_kernel<<<(PREP_T + 255) / 256, 256, 0, stream>>>(
        W2, al2, ar2, W3, al3, ar3, aleff2, areff2, aleff3, areff3, W4t2, wfrag3, counts);

    hist_kernel<<<(N_EDGES + 255) / 256, 256, 0, stream>>>(dst, counts);
    scan_kernel<<<1, 256, 0, stream>>>(counts, row_ptr);
    build_csr_kernel<<<(N_NODES * 64 + 255) / 256, 256, 0, stream>>>(dst, src, row_ptr, csr_src);

    // ---- layer 1 ----
    dim3 g1(512 / BN, (N_NODES + BM - 1) / BM);
    gemm_f32<<<g1, 256, 0, stream>>>(node, W1, feat1, N_NODES, 512, IN_FEAT);
    elr_feat_kernel<<<(N_NODES * 8 + 255) / 256, 256, 0, stream>>>(feat1, al1, ar1, el1, er1, N_NODES * 8);
    agg_l1<<<N_NODES, 256, 0, stream>>>(feat1, el1, er1, b1, row_ptr, csr_src, h1);

    // ---- layer 2 ----
    elr_row_kernel<<<(N_NODES * 8 + 255) / 256, 256, 0, stream>>>(h1, aleff2, areff2, el2, er2, N_NODES * 8);
    agg_fused4<64, true, 8><<<N_NODES, 256, 0, stream>>>(h1, el2, er2, W4t2, b2, row_ptr, csr_src, h2);

    // ---- layer 3 ----
    elr_row_kernel<<<(N_NODES * 64 + 255) / 256, 256, 0, stream>>>(h2, aleff3, areff3, el3, er3, N_NODES * 64);
    agg_mfma3<<<N_NODES * 4, 256, 0, stream>>>(h2, el3, er3, wfrag3, b3, row_ptr, csr_src, out);
}